// Round 13
// baseline (215.673 us; speedup 1.0000x reference)
//
#include <hip/hip_runtime.h>
#include <hip/hip_bf16.h>
#include <math.h>

// ---------------------------------------------------------------------------
// Seq_HyGAN round 13:
//  * attn_s1: 4-edge batched gather (8 rows in flight), 1 rescale per quad.
//  * head2 fused into attn_s2 merge (agg buffer + 10MB traffic + launch gone).
//  * dotc2 folded into gemm_m (y==6); zero_ints folded into prep_a (runs 1st).
//  * CSR chunks 4096->1024 (coarse_hist/part_scatter grids 157->625 blocks).
//  12 launches (was 15). Everything else as round 12.
// ---------------------------------------------------------------------------

#define HY_M 10000
#define HY_N 100000
#define HY_E 640000

#define SH_N 9              // node bucket width 512
#define NB_N 196            // ceil(100000/512)
#define SH_M 6              // hedge bucket width 64
#define NB_M 157            // ceil(10000/64)

typedef float        f32x4 __attribute__((ext_vector_type(4)));
typedef unsigned int u32x4 __attribute__((ext_vector_type(4)));

// ---- bf16 helpers (manual, RN) ----
__device__ __forceinline__ unsigned int f2bf(float x) {
    unsigned int u = __float_as_uint(x);
    return (u + 0x7fffu + ((u >> 16) & 1u)) >> 16;
}
__device__ __forceinline__ float2 bf2x2(unsigned int w) {
    float lo = __uint_as_float(w << 16);
    float hi = __uint_as_float(w & 0xffff0000u);
    return make_float2(lo, hi);
}
__device__ __forceinline__ float dot8(uint4 kw, float4 qa, float4 qb) {
    float2 k0 = bf2x2(kw.x), k1 = bf2x2(kw.y), k2 = bf2x2(kw.z), k3 = bf2x2(kw.w);
    return k0.x * qa.x + k0.y * qa.y + k1.x * qa.z + k1.y * qa.w
         + k2.x * qb.x + k2.y * qb.y + k3.x * qb.z + k3.y * qb.w;
}
__device__ __forceinline__ void unpack8(uint4 vw, float (&vf)[8]) {
    float2 v0 = bf2x2(vw.x), v1 = bf2x2(vw.y), v2 = bf2x2(vw.z), v3 = bf2x2(vw.w);
    vf[0] = v0.x; vf[1] = v0.y; vf[2] = v1.x; vf[3] = v1.y;
    vf[4] = v2.x; vf[5] = v2.y; vf[6] = v3.x; vf[7] = v3.y;
}
__device__ __forceinline__ float red16(float d) {
    d += __shfl_xor(d, 8); d += __shfl_xor(d, 4);
    d += __shfl_xor(d, 2); d += __shfl_xor(d, 1);
    return d;
}

// ---------------- CSR build: bucketed counting sort (1024-edge chunks) ------
__launch_bounds__(256)
__global__ void coarse_hist(const int* __restrict__ nd, const int* __restrict__ he,
                            int* __restrict__ gcntN, int* __restrict__ gcntM, int E) {
    __shared__ int hN[256], hM[256];
    const int t = threadIdx.x;
    hN[t] = 0; hM[t] = 0;
    __syncthreads();
    const int base = blockIdx.x * 1024;
    for (int i = t; i < 1024; i += 256) {
        int e = base + i;
        if (e < E) {
            atomicAdd(&hN[nd[e] >> SH_N], 1);
            atomicAdd(&hM[he[e] >> SH_M], 1);
        }
    }
    __syncthreads();
    if (hN[t]) atomicAdd(&gcntN[t], hN[t]);
    if (hM[t]) atomicAdd(&gcntM[t], hM[t]);
}

__global__ void coarse_scan(const int* __restrict__ gcntN, const int* __restrict__ gcntM,
                            int* __restrict__ coffN, int* __restrict__ coffM, int E) {
    __shared__ int s[256];
    const int* g = blockIdx.x ? gcntM : gcntN;
    int* o = blockIdx.x ? coffM : coffN;
    const int nb = blockIdx.x ? NB_M : NB_N;
    const int t = threadIdx.x;
    int v = (t < nb) ? g[t] : 0;
    int orig = v;
    s[t] = v; __syncthreads();
    for (int off = 1; off < 256; off <<= 1) {
        int x = (t >= off) ? s[t - off] : 0;
        __syncthreads(); s[t] += x; __syncthreads();
    }
    if (t < nb) o[t] = s[t] - orig;
    if (t == 0) o[nb] = E;
}

__launch_bounds__(256)
__global__ void part_scatter(const int* __restrict__ nd, const int* __restrict__ he,
                             const int* __restrict__ coffN, const int* __restrict__ coffM,
                             int* __restrict__ gcurN, int* __restrict__ gcurM,
                             unsigned int* __restrict__ stN, unsigned int* __restrict__ stM,
                             int E) {
    __shared__ int hN[256], hM[256];
    const int t = threadIdx.x;
    hN[t] = 0; hM[t] = 0;
    __syncthreads();
    const int base = blockIdx.x * 1024;
    for (int i = t; i < 1024; i += 256) {
        int e = base + i;
        if (e < E) {
            atomicAdd(&hN[nd[e] >> SH_N], 1);
            atomicAdd(&hM[he[e] >> SH_M], 1);
        }
    }
    __syncthreads();
    int cN = hN[t], cM = hM[t];
    __syncthreads();
    if (cN) hN[t] = coffN[t] + atomicAdd(&gcurN[t], cN);
    if (cM) hM[t] = coffM[t] + atomicAdd(&gcurM[t], cM);
    __syncthreads();
    for (int i = t; i < 1024; i += 256) {
        int e = base + i;
        if (e < E) {
            int d = nd[e], h = he[e];
            int pN = atomicAdd(&hN[d >> SH_N], 1);
            stN[pN] = ((unsigned int)(d & 511) << 14) | (unsigned int)h;
            int pM = atomicAdd(&hM[h >> SH_M], 1);
            stM[pM] = ((unsigned int)(h & 63) << 17) | (unsigned int)d;
        }
    }
}

// + folded node-degree histogram (feeds nperm build)
__launch_bounds__(256)
__global__ void bucket_build(const unsigned int* __restrict__ stN,
                             const unsigned int* __restrict__ stM,
                             const int* __restrict__ coffN, const int* __restrict__ coffM,
                             int* __restrict__ nd_off, int* __restrict__ he_off,
                             int* __restrict__ nd_adj, int* __restrict__ he_adj,
                             int* __restrict__ dcntg) {
    __shared__ int cnt[512];
    __shared__ int cur[512];
    __shared__ int ps[256];
    __shared__ int dh[64];
    int b = blockIdx.x;
    const int t = threadIdx.x;
    const unsigned int* st; const int* coff; int* offout; int* adj;
    int dmin, dcnt2, sshift; unsigned int smask; int ntot;
    const bool isN = b < NB_N;
    if (isN) {
        st = stN; coff = coffN; offout = nd_off; adj = nd_adj;
        dmin = b << SH_N; dcnt2 = min(512, HY_N - dmin);
        sshift = 14; smask = 0x3FFFu; ntot = HY_N;
    } else {
        b -= NB_N;
        st = stM; coff = coffM; offout = he_off; adj = he_adj;
        dmin = b << SH_M; dcnt2 = min(64, HY_M - dmin);
        sshift = 17; smask = 0x1FFFFu; ntot = HY_M;
    }
    const int cbase = coff[b], cend = coff[b + 1];
    cnt[t] = 0; cnt[t + 256] = 0;
    if (t < 64) dh[t] = 0;
    __syncthreads();
    for (int k = cbase + t; k < cend; k += 256)
        atomicAdd(&cnt[st[k] >> sshift], 1);
    __syncthreads();
    int a0 = cnt[2 * t], a1 = cnt[2 * t + 1];
    int pair = a0 + a1;
    ps[t] = pair;
    __syncthreads();
    for (int off = 1; off < 256; off <<= 1) {
        int x = (t >= off) ? ps[t - off] : 0;
        __syncthreads(); ps[t] += x; __syncthreads();
    }
    int excl = ps[t] - pair;
    cur[2 * t]     = cbase + excl;
    cur[2 * t + 1] = cbase + excl + a0;
    __syncthreads();
    for (int i = t; i < dcnt2; i += 256) offout[dmin + i] = cur[i];
    if (t == 0 && dmin + dcnt2 == ntot) offout[ntot] = cend;
    if (isN) {
        for (int i = t; i < dcnt2; i += 256)
            atomicAdd(&dh[min(cnt[i], 63)], 1);
    }
    __syncthreads();
    if (isN && t < 64 && dh[t]) atomicAdd(&dcntg[t], dh[t]);
    for (int k = cbase + t; k < cend; k += 256) {
        unsigned int w = st[k];
        int pos = atomicAdd(&cur[w >> sshift], 1);
        adj[pos] = (int)(w & smask);
    }
}

// ---------------- degree-sorted node permutation (DESCENDING = LPT) ---------
__global__ void deg_scan(const int* __restrict__ dcnt, int* __restrict__ dcur) {
    int t = threadIdx.x;   // 64 threads = 1 wave
    int rt = 63 - t;
    int v = dcnt[rt];
    int s = v;
    for (int o = 1; o < 64; o <<= 1) {
        int x = __shfl_up(s, o, 64);
        if (t >= o) s += x;
    }
    dcur[rt] = s - v;
}

__launch_bounds__(256)
__global__ void deg_scatter(const int* __restrict__ off, int* __restrict__ dcur,
                            int* __restrict__ nperm, int n) {
    __shared__ int h[64];
    __shared__ int basev[64];
    int t = threadIdx.x;
    if (t < 64) h[t] = 0;
    __syncthreads();
    int i = blockIdx.x * blockDim.x + t;
    int bin = 0, lpos = 0;
    bool valid = i < n;
    if (valid) {
        bin = min(off[i + 1] - off[i], 63);
        lpos = atomicAdd(&h[bin], 1);
    }
    __syncthreads();
    if (t < 64 && h[t]) basev[t] = atomicAdd(&dcur[t], h[t]);
    __syncthreads();
    if (valid) nperm[basev[bin] + lpos] = i;
}

// ---------------- f32 GEMM core for 128x128 weight products ----------------
__device__ __forceinline__ void gemm_accum(const float* __restrict__ A,
        const float* __restrict__ W, int nrows, float* wlds,
        float (&acc)[4][4], int row0) {
    const int tid = threadIdx.x;
    const int cg = tid & 31;
    for (int i = tid; i < 4096; i += 512)
        ((float4*)wlds)[i] = ((const float4*)W)[i];
    __syncthreads();
    const float4* A0 = (const float4*)(A + (size_t)min(row0 + 0, nrows - 1) * 128);
    const float4* A1 = (const float4*)(A + (size_t)min(row0 + 1, nrows - 1) * 128);
    const float4* A2 = (const float4*)(A + (size_t)min(row0 + 2, nrows - 1) * 128);
    const float4* A3 = (const float4*)(A + (size_t)min(row0 + 3, nrows - 1) * 128);
    #pragma unroll 2
    for (int kq = 0; kq < 32; ++kq) {
        float4 ar[4] = {A0[kq], A1[kq], A2[kq], A3[kq]};
        const float4* wk = (const float4*)(wlds + kq * 512);
        float4 wr[4] = {wk[cg], wk[32 + cg], wk[64 + cg], wk[96 + cg]};
        #pragma unroll
        for (int r = 0; r < 4; ++r) {
            float av[4] = {ar[r].x, ar[r].y, ar[r].z, ar[r].w};
            #pragma unroll
            for (int j = 0; j < 4; ++j) {
                float wv[4] = {wr[j].x, wr[j].y, wr[j].z, wr[j].w};
                #pragma unroll
                for (int c = 0; c < 4; ++c)
                    acc[r][c] = fmaf(av[j], wv[c], acc[r][c]);
            }
        }
    }
}

__device__ __forceinline__ void gemm_store_f32(const float* __restrict__ b,
        float* __restrict__ Cf, int nrows, float (&acc)[4][4], int row0) {
    const int cg = threadIdx.x & 31;
    const float4 bv = ((const float4*)b)[cg];
    #pragma unroll
    for (int r = 0; r < 4; ++r) {
        int gr = row0 + r;
        if (gr < nrows) {
            float4 o = {acc[r][0] + bv.x, acc[r][1] + bv.y,
                        acc[r][2] + bv.z, acc[r][3] + bv.w};
            ((float4*)(Cf + (size_t)gr * 128))[cg] = o;
        }
    }
}

// y=0: W12=W1@W2T ; y=1: W54=W5@W4T
__launch_bounds__(512)
__global__ void gemm_pair(const float* __restrict__ Aa, const float* __restrict__ Wa,
                          float* __restrict__ Ca,
                          const float* __restrict__ Ab, const float* __restrict__ Wb,
                          float* __restrict__ Cb2, const float* __restrict__ zb) {
    __shared__ __align__(16) float wlds[16384];
    const int rs = threadIdx.x >> 5;
    const int row0 = blockIdx.x * 64 + rs * 4;
    const float* A = blockIdx.y ? Ab : Aa;
    const float* W = blockIdx.y ? Wb : Wa;
    float* C = blockIdx.y ? Cb2 : Ca;
    float acc[4][4] = {};
    gemm_accum(A, W, 128, wlds, acc, row0);
    gemm_store_f32(zb, C, 128, acc, row0);
}

// y=0..2: Wk/Wv/Wq = Wfl @ {W54,W6,W12} ; y=3,x=0: prep_fold
__launch_bounds__(512)
__global__ void gemm_trip(const float* __restrict__ Wfl, const float* __restrict__ bfl,
        const float* __restrict__ W54, const float* __restrict__ b54v,
        const float* __restrict__ W6, const float* __restrict__ b6,
        const float* __restrict__ W12, const float* __restrict__ b12v,
        const float* __restrict__ w1b2, const float* __restrict__ s12,
        const float* __restrict__ w5b4, const float* __restrict__ s54,
        float* __restrict__ Wk, float* __restrict__ Wv, float* __restrict__ Wq,
        float* __restrict__ bk, float* __restrict__ bv, float* __restrict__ bq,
        float* __restrict__ u_c, float* __restrict__ u_k,
        float* __restrict__ t_c, float* __restrict__ t_k,
        const float* __restrict__ zb) {
    __shared__ __align__(16) float wlds[16384];
    const int y = blockIdx.y;
    if (y == 3) {
        if (blockIdx.x != 0) return;
        int t = threadIdx.x;
        if (t < 128) {
            float a1 = 0.f, a2 = 0.f, a3 = 0.f;
            for (int j = 0; j < 128; ++j) {
                float f = bfl[j];
                a1 += f * W54[j * 128 + t];
                a2 += f * W6[j * 128 + t];
                a3 += f * W12[j * 128 + t];
            }
            bk[t] = a1 + b54v[t];
            bv[t] = a2 + b6[t];
            bq[t] = a3 + b12v[t];
        } else if (t < 256) {
            int k = t - 128;
            float a1 = 0.f, a2 = 0.f;
            for (int j = 0; j < 128; ++j) {
                float f = Wfl[k * 128 + j];
                a1 += f * w1b2[j];
                a2 += f * w5b4[j];
            }
            u_c[k] = a1;
            u_k[k] = a2;
        }
        if (t == 0) {
            float a1 = 0.f, a2 = 0.f;
            for (int j = 0; j < 128; ++j) {
                a1 += bfl[j] * w1b2[j];
                a2 += bfl[j] * w5b4[j];
            }
            *t_c = a1 + *s12;
            *t_k = a2 + *s54;
        }
        return;
    }
    const int rs = threadIdx.x >> 5;
    const int row0 = blockIdx.x * 64 + rs * 4;
    const float* W = y == 0 ? W54 : (y == 1 ? W6 : W12);
    float* C = y == 0 ? Wk : (y == 1 ? Wv : Wq);
    float acc[4][4] = {};
    gemm_accum(Wfl, W, 128, wlds, acc, row0);
    gemm_store_f32(zb, C, 128, acc, row0);
}

// ---------------- main M-row batched GEMM + dots (y==6) ----------------
__launch_bounds__(256)
__global__ void gemm_m(const float* __restrict__ A,
        const float* __restrict__ Wk, const float* __restrict__ bk,
        const float* __restrict__ Wv, const float* __restrict__ bvv,
        const float* __restrict__ Wq, const float* __restrict__ bq,
        const float* __restrict__ u_c, const float* __restrict__ t_c,
        const float* __restrict__ u_k, const float* __restrict__ t_k,
        float* __restrict__ c_e, float* __restrict__ ck,
        unsigned short* __restrict__ kv, float* __restrict__ qt, int nrows) {
    __shared__ __align__(16) float wlds[128 * 64];
    const int tid = threadIdx.x;
    if (blockIdx.y == 6) {                 // dotc2 rows
        const int w = tid >> 6, lane = tid & 63;
        float2 a1 = ((const float2*)u_c)[lane];
        float2 a2 = ((const float2*)u_k)[lane];
        for (int it = 0; it < 8; ++it) {
            int row = blockIdx.x * 32 + it * 4 + w;
            if (row < nrows) {
                float2 r = ((const float2*)(A + (size_t)row * 128))[lane];
                float d1 = r.x * a1.x + r.y * a1.y;
                float d2 = r.x * a2.x + r.y * a2.y;
                #pragma unroll
                for (int o = 32; o; o >>= 1) {
                    d1 += __shfl_xor(d1, o, 64);
                    d2 += __shfl_xor(d2, o, 64);
                }
                if (lane == 0) { c_e[row] = d1 + *t_c; ck[row] = d2 + *t_k; }
            }
        }
        return;
    }
    const int mat = blockIdx.y >> 1;
    const int half = blockIdx.y & 1;
    const float* W = mat == 0 ? Wk : (mat == 1 ? Wv : Wq);
    const float* bb = mat == 0 ? bk : (mat == 1 ? bvv : bq);
    const float4* W4 = (const float4*)W;
    float4* wl4 = (float4*)wlds;
    for (int i = tid; i < 2048; i += 256)
        wl4[i] = W4[(i >> 4) * 32 + half * 16 + (i & 15)];
    __syncthreads();
    const int cg = tid & 15;
    const int rs = tid >> 4;
    const int row0 = blockIdx.x * 32 + rs * 2;
    const float4* A0 = (const float4*)(A + (size_t)min(row0, nrows - 1) * 128);
    const float4* A1 = (const float4*)(A + (size_t)min(row0 + 1, nrows - 1) * 128);
    float acc[2][4] = {};
    #pragma unroll 4
    for (int kq = 0; kq < 32; ++kq) {
        float4 a0 = A0[kq], a1 = A1[kq];
        float av0[4] = {a0.x, a0.y, a0.z, a0.w};
        float av1[4] = {a1.x, a1.y, a1.z, a1.w};
        #pragma unroll
        for (int jj = 0; jj < 4; ++jj) {
            float4 w4 = wl4[(4 * kq + jj) * 16 + cg];
            float wv4[4] = {w4.x, w4.y, w4.z, w4.w};
            #pragma unroll
            for (int c = 0; c < 4; ++c) {
                acc[0][c] = fmaf(av0[jj], wv4[c], acc[0][c]);
                acc[1][c] = fmaf(av1[jj], wv4[c], acc[1][c]);
            }
        }
    }
    const float4 bv4 = ((const float4*)bb)[half * 16 + cg];
    #pragma unroll
    for (int r = 0; r < 2; ++r) {
        int gr = row0 + r;
        if (gr < nrows) {
            float o0 = acc[r][0] + bv4.x, o1 = acc[r][1] + bv4.y;
            float o2 = acc[r][2] + bv4.z, o3 = acc[r][3] + bv4.w;
            if (mat == 2) {
                float4 o = {o0, o1, o2, o3};
                ((float4*)(qt + (size_t)gr * 128))[half * 16 + cg] = o;
            } else {
                uint2 pk;
                pk.x = f2bf(o0) | (f2bf(o1) << 16);
                pk.y = f2bf(o2) | (f2bf(o3) << 16);
                *(uint2*)(kv + (size_t)gr * 256 + mat * 128 + half * 64 + cg * 4) = pk;
            }
        }
    }
}

// ---------------- fused precompute kernel (142 blocks, runs FIRST) ----------
__device__ __forceinline__ void prep_vecs_body(const float* WX, const float* WY,
        const float* bX, const float* bY, float* bXY, float* wXbY, float* sXY, int t) {
    if (t < 128) {
        float acc = 0.f;
        for (int j = 0; j < 128; ++j) acc += WY[t * 128 + j] * bX[j];
        bXY[t] = acc;
    } else {
        int k = t - 128;
        float acc = 0.f;
        for (int j = 0; j < 128; ++j) acc += WX[k * 128 + j] * bY[j];
        wXbY[k] = acc;
    }
    if (t == 0) {
        float acc = 0.f;
        for (int j = 0; j < 128; ++j) acc += bX[j] * bY[j];
        *sXY = acc;
    }
}

__global__ void prep_a(const float* __restrict__ W1, const float* __restrict__ b1,
                       const float* __restrict__ W2, const float* __restrict__ b2,
                       const float* __restrict__ W3, const float* __restrict__ b3,
                       const float* __restrict__ W4, const float* __restrict__ b4,
                       const float* __restrict__ W5, const float* __restrict__ b5,
                       const float* __restrict__ Wc,
                       float* __restrict__ W2T, float* __restrict__ W4T,
                       float* __restrict__ b12v, float* __restrict__ w1b2,
                       float* __restrict__ s12,
                       float* __restrict__ b54v, float* __restrict__ w5b4,
                       float* __restrict__ s54,
                       float* __restrict__ W3c, float* __restrict__ b3c,
                       float* __restrict__ zeros, int* __restrict__ zint) {
    const int x = blockIdx.x, t = threadIdx.x;
    if (x < 64) {
        int i = x * 256 + t;
        W2T[(i & 127) * 128 + (i >> 7)] = W2[i];
    } else if (x < 128) {
        int i = (x - 64) * 256 + t;
        W4T[(i & 127) * 128 + (i >> 7)] = W4[i];
    } else if (x == 128) {
        prep_vecs_body(W1, W2, b1, b2, b12v, w1b2, s12, t);
    } else if (x == 129) {
        prep_vecs_body(W5, W4, b5, b4, b54v, w5b4, s54, t);
    } else if (x < 136) {
        int i = (x - 130) * 256 + t;
        if (i < 1280) {
            int k = i / 10, c = i % 10;
            float acc = 0.f;
            for (int j = 0; j < 128; ++j) acc += W3[k * 128 + j] * Wc[j * 10 + c];
            W3c[i] = acc;
        } else if (i < 1290) {
            int c = i - 1280;
            float acc = 0.f;
            for (int j = 0; j < 128; ++j) acc += b3[j] * Wc[j * 10 + c];
            b3c[c] = acc;
        }
    } else if (x == 136) {
        if (t < 128) zeros[t] = 0.f;
    } else {                                   // x = 137..141: zero 1152 ints
        int i = (x - 137) * 256 + t;
        if (i < 1152) zint[i] = 0;
    }
}

// ---------------- stage 1: hyperedge -> node (4-edge batch) -----------------
__launch_bounds__(256)
__global__ void attn_s1(const float* __restrict__ vf,          // N x 128 f32
                        const unsigned int* __restrict__ kv,   // M x 128 words (kt|v)
                        const float* __restrict__ ck,          // M
                        const int* __restrict__ off, const int* __restrict__ adj,
                        const int* __restrict__ nperm,
                        unsigned int* __restrict__ fv,         // N x 64 words
                        int nseg, float scale) {
    int slot = (blockIdx.x * blockDim.x + threadIdx.x) >> 4;
    int j = threadIdx.x & 15;
    if (slot >= nseg) return;
    int seg = nperm[slot];
    int beg = off[seg], end = off[seg + 1];
    const f32x4* qp = (const f32x4*)(vf + (size_t)seg * 128 + 8 * j);
    f32x4 qa4 = __builtin_nontemporal_load(qp);
    f32x4 qb4 = __builtin_nontemporal_load(qp + 1);
    float4 qa = {qa4.x, qa4.y, qa4.z, qa4.w};
    float4 qb = {qb4.x, qb4.y, qb4.z, qb4.w};
    float m = -INFINITY, l = 0.f;
    float a[8] = {};
    int i = beg;
    for (; i + 3 < end; i += 4) {              // quads: 8 gathers in flight
        int s0 = adj[i], s1 = adj[i + 1], s2 = adj[i + 2], s3 = adj[i + 3];
        const uint4* r0 = (const uint4*)(kv + (size_t)s0 * 128);
        const uint4* r1 = (const uint4*)(kv + (size_t)s1 * 128);
        const uint4* r2 = (const uint4*)(kv + (size_t)s2 * 128);
        const uint4* r3 = (const uint4*)(kv + (size_t)s3 * 128);
        uint4 k0 = r0[j], k1 = r1[j], k2 = r2[j], k3 = r3[j];
        uint4 v0 = r0[16 + j], v1 = r1[16 + j], v2 = r2[16 + j], v3 = r3[16 + j];
        float c0 = ck[s0], c1 = ck[s1], c2 = ck[s2], c3 = ck[s3];
        float d0 = dot8(k0, qa, qb), d1 = dot8(k1, qa, qb);
        float d2 = dot8(k2, qa, qb), d3 = dot8(k3, qa, qb);
        #pragma unroll
        for (int o = 8; o; o >>= 1) {
            d0 += __shfl_xor(d0, o); d1 += __shfl_xor(d1, o);
            d2 += __shfl_xor(d2, o); d3 += __shfl_xor(d3, o);
        }
        d0 += c0; d1 += c1; d2 += c2; d3 += c3;
        d0 = (d0 >= 0.f ? d0 : 0.01f * d0) * scale;
        d1 = (d1 >= 0.f ? d1 : 0.01f * d1) * scale;
        d2 = (d2 >= 0.f ? d2 : 0.01f * d2) * scale;
        d3 = (d3 >= 0.f ? d3 : 0.01f * d3) * scale;
        float mn = fmaxf(fmaxf(fmaxf(d0, d1), fmaxf(d2, d3)), m);
        float r  = __expf(m - mn);             // first quad: exp(-inf)=0
        float p0 = __expf(d0 - mn), p1 = __expf(d1 - mn);
        float p2 = __expf(d2 - mn), p3 = __expf(d3 - mn);
        l = l * r + p0 + p1 + p2 + p3;
        float w0[8], w1[8], w2[8], w3[8];
        unpack8(v0, w0); unpack8(v1, w1); unpack8(v2, w2); unpack8(v3, w3);
        #pragma unroll
        for (int t = 0; t < 8; ++t)
            a[t] = fmaf(p3, w3[t], fmaf(p2, w2[t],
                   fmaf(p1, w1[t], fmaf(p0, w0[t], a[t] * r))));
        m = mn;
    }
    for (; i < end; ++i) {                     // 0-3 tail edges
        int s0 = adj[i];
        const uint4* r0 = (const uint4*)(kv + (size_t)s0 * 128);
        uint4 k0 = r0[j], v0 = r0[16 + j];
        float d = dot8(k0, qa, qb);
        d = red16(d);
        d += ck[s0];
        d = (d >= 0.f ? d : 0.01f * d) * scale;
        float mn = fmaxf(m, d);
        float r = __expf(m - mn);
        float p = __expf(d - mn);
        l = l * r + p;
        float w0[8]; unpack8(v0, w0);
        #pragma unroll
        for (int t = 0; t < 8; ++t) a[t] = fmaf(p, w0[t], a[t] * r);
        m = mn;
    }
    float inv = (l > 0.f) ? 1.f / l : 0.f;
    u32x4 o;
    o.x = f2bf(a[0] * inv) | (f2bf(a[1] * inv) << 16);
    o.y = f2bf(a[2] * inv) | (f2bf(a[3] * inv) << 16);
    o.z = f2bf(a[4] * inv) | (f2bf(a[5] * inv) << 16);
    o.w = f2bf(a[6] * inv) | (f2bf(a[7] * inv) << 16);
    __builtin_nontemporal_store(o, (u32x4*)(fv + (size_t)seg * 64 + 4 * j));
}

// ---------------- stage 2: node -> hyperedge (fused head) -------------------
__launch_bounds__(256)
__global__ void attn_s2(const float* __restrict__ QT, const float* __restrict__ cvec,
                        const unsigned int* __restrict__ fv,
                        const int* __restrict__ off, const int* __restrict__ adj,
                        const float* __restrict__ W3c, const float* __restrict__ b3c,
                        const float* __restrict__ bc, float* __restrict__ out,
                        float scale) {
    __shared__ float sm[16], sl[16];
    __shared__ float sacc[16][16][9];
    const int seg = blockIdx.x;
    const int g = threadIdx.x >> 4;
    const int j = threadIdx.x & 15;
    const int beg = off[seg], end = off[seg + 1];
    const f32x4* qp = (const f32x4*)(QT + (size_t)seg * 128 + 8 * j);
    f32x4 qa4 = __builtin_nontemporal_load(qp);
    f32x4 qb4 = __builtin_nontemporal_load(qp + 1);
    float4 qa = {qa4.x, qa4.y, qa4.z, qa4.w};
    float4 qb = {qb4.x, qb4.y, qb4.z, qb4.w};
    const float cadd = cvec[seg];
    float m = -INFINITY, l = 0.f;
    float a[8] = {};
    int it = beg + g;
    if (it + 16 < end) {
        int s0 = adj[it], s1 = adj[it + 16];
        uint4 rw0 = ((const uint4*)(fv + (size_t)s0 * 64))[j];
        uint4 rw1 = ((const uint4*)(fv + (size_t)s1 * 64))[j];
        for (; it + 16 < end; it += 32) {
            uint4 ra = rw0, rb = rw1;
            if (it + 48 < end) {
                int t0 = adj[it + 32], t1 = adj[it + 48];
                rw0 = ((const uint4*)(fv + (size_t)t0 * 64))[j];
                rw1 = ((const uint4*)(fv + (size_t)t1 * 64))[j];
            } else if (it + 32 < end) {
                int t0 = adj[it + 32];
                rw0 = ((const uint4*)(fv + (size_t)t0 * 64))[j];
            }
            float v1[8], v2[8];
            unpack8(ra, v1); unpack8(rb, v2);
            float d1 = v1[0] * qa.x + v1[1] * qa.y + v1[2] * qa.z + v1[3] * qa.w
                     + v1[4] * qb.x + v1[5] * qb.y + v1[6] * qb.z + v1[7] * qb.w;
            float d2 = v2[0] * qa.x + v2[1] * qa.y + v2[2] * qa.z + v2[3] * qa.w
                     + v2[4] * qb.x + v2[5] * qb.y + v2[6] * qb.z + v2[7] * qb.w;
            #pragma unroll
            for (int o = 8; o; o >>= 1) { d1 += __shfl_xor(d1, o); d2 += __shfl_xor(d2, o); }
            d1 += cadd; d2 += cadd;
            d1 = (d1 >= 0.f ? d1 : 0.01f * d1) * scale;
            d2 = (d2 >= 0.f ? d2 : 0.01f * d2) * scale;
            float mn = fmaxf(fmaxf(m, d1), d2);
            float r  = __expf(m - mn);
            float p1 = __expf(d1 - mn);
            float p2 = __expf(d2 - mn);
            l = l * r + p1 + p2;
            #pragma unroll
            for (int t = 0; t < 8; ++t)
                a[t] = fmaf(p2, v2[t], fmaf(p1, v1[t], a[t] * r));
            m = mn;
        }
        if (it < end) {
            float v1[8]; unpack8(rw0, v1);
            float d = v1[0] * qa.x + v1[1] * qa.y + v1[2] * qa.z + v1[3] * qa.w
                    + v1[4] * qb.x + v1[5] * qb.y + v1[6] * qb.z + v1[7] * qb.w;
            d = red16(d);
            d += cadd;
            d = (d >= 0.f ? d : 0.01f * d) * scale;
            float mn = fmaxf(m, d);
            float r = __expf(m - mn);
            float p = __expf(d - mn);
            l = l * r + p;
            #pragma unroll
            for (int t = 0; t < 8; ++t) a[t] = fmaf(p, v1[t], a[t] * r);
            m = mn;
        }
    } else if (it < end) {
        int s0 = adj[it];
        uint4 rw0 = ((const uint4*)(fv + (size_t)s0 * 64))[j];
        float v1[8]; unpack8(rw0, v1);
        float d = v1[0] * qa.x + v1[1] * qa.y + v1[2] * qa.z + v1[3] * qa.w
                + v1[4] * qb.x + v1[5] * qb.y + v1[6] * qb.z + v1[7] * qb.w;
        d = red16(d);
        d += cadd;
        d = (d >= 0.f ? d : 0.01f * d) * scale;
        m = d; l = 1.f;
        #pragma unroll
        for (int t = 0; t < 8; ++t) a[t] = v1[t];
    }
    if (j == 0) { sm[g] = m; sl[g] = l; }
    #pragma unroll
    for (int t = 0; t < 8; ++t) sacc[g][j][t] = a[t];
    __syncthreads();
    if (threadIdx.x < 16) {                    // lanes 0-15 of wave 0
        const int t16 = threadIdx.x;
        float M2 = -INFINITY;
        #pragma unroll 4
        for (int gg = 0; gg < 16; ++gg) if (sl[gg] > 0.f) M2 = fmaxf(M2, sm[gg]);
        float L = 0.f;
        float acc[8] = {};
        #pragma unroll 4
        for (int gg = 0; gg < 16; ++gg) {
            float f = (sl[gg] > 0.f) ? __expf(sm[gg] - M2) : 0.f;
            L += f * sl[gg];
            #pragma unroll
            for (int t = 0; t < 8; ++t) acc[t] += f * sacc[gg][t16][t];
        }
        float inv = (L > 0.f) ? 1.f / L : 0.f;
        float fl  = (L > 0.f) ? 1.f : 0.f;
        #pragma unroll
        for (int t = 0; t < 8; ++t) acc[t] *= inv;
        // fused head: pred = agg @ W3c + fl*b3c + bc   (this thread's 8 dims)
        float pp[10];
        #pragma unroll
        for (int c = 0; c < 10; ++c) {
            float s = 0.f;
            #pragma unroll
            for (int t = 0; t < 8; ++t)
                s = fmaf(acc[t], W3c[(8 * t16 + t) * 10 + c], s);
            pp[c] = s;
        }
        #pragma unroll
        for (int o = 8; o; o >>= 1) {
            #pragma unroll
            for (int c = 0; c < 10; ++c) pp[c] += __shfl_xor(pp[c], o);
        }
        if (t16 == 0) {
            #pragma unroll
            for (int c = 0; c < 10; ++c)
                out[(size_t)seg * 10 + c] = pp[c] + fl * b3c[c] + bc[c];
        }
    }
}

extern "C" void kernel_launch(void* const* d_in, const int* in_sizes, int n_in,
                              void* d_out, int out_size, void* d_ws, size_t ws_size,
                              hipStream_t stream) {
    const float* vfeat = (const float*)d_in[0];
    const float* efeat = (const float*)d_in[1];
    const int*   he    = (const int*)d_in[2];
    const int*   nd    = (const int*)d_in[3];
    const float* Wfl = (const float*)d_in[6],  *bfl = (const float*)d_in[7];
    const float* W1  = (const float*)d_in[8],  *b1  = (const float*)d_in[9];
    const float* W2  = (const float*)d_in[10], *b2  = (const float*)d_in[11];
    const float* W3  = (const float*)d_in[12], *b3  = (const float*)d_in[13];
    const float* W4  = (const float*)d_in[14], *b4  = (const float*)d_in[15];
    const float* W5  = (const float*)d_in[16], *b5  = (const float*)d_in[17];
    const float* W6  = (const float*)d_in[18], *b6  = (const float*)d_in[19];
    const float* Wc  = (const float*)d_in[20], *bc  = (const float*)d_in[21];
    float* out = (float*)d_out;
    float* ws  = (float*)d_ws;

    const int M = HY_M, N = HY_N, E = HY_E;

    // -------- workspace layout (float units) --------
    float* qt_e  = ws + 0;         // 1,280,000
    float* c_e   = ws + 1280000;   // 10,000
    float* ck    = ws + 1290000;   // 10,000
    float* W2T   = ws + 1300000;   // 16384
    float* W4T   = ws + 1316384;   // 16384
    float* W12   = ws + 1332768;   // 16384
    float* W54   = ws + 1349152;   // 16384
    float* Wk    = ws + 1365536;   // 16384
    float* Wv    = ws + 1381920;   // 16384
    float* Wq    = ws + 1398304;   // 16384
    float* W3c   = ws + 1414688;   // 1280
    float* b3c   = ws + 1415968;   // 16
    float* b12v  = ws + 1415984;   // 128
    float* w1b2  = ws + 1416112;   // 128
    float* s12   = ws + 1416240;   // 4
    float* b54v  = ws + 1416244;   // 128
    float* w5b4  = ws + 1416372;   // 128
    float* s54   = ws + 1416500;   // 4
    float* bk    = ws + 1416504;   // 128
    float* bv    = ws + 1416632;   // 128
    float* bq    = ws + 1416760;   // 128
    float* u_c   = ws + 1416888;   // 128
    float* u_k   = ws + 1417016;   // 128
    float* t_c   = ws + 1417144;   // 4
    float* t_k   = ws + 1417148;   // 4
    float* zeros = ws + 1417152;   // 128 (ends 1417280)
    unsigned int* kv_bf = (unsigned int*)(ws + 1417280);   // M*128 words
    unsigned int* fv_bf = kv_bf + (size_t)M * 128;         // N*64 words
    int* nd_off = (int*)(fv_bf + (size_t)N * 64);          // 100,001
    int* he_off = nd_off + 100001;                          // 10,001
    int* nd_adj = he_off + 10001;                           // 640,000
    int* he_adj = nd_adj + 640000;                          // 640,000
    int* nperm  = he_adj + 640000;                          // 100,000
    unsigned int* stN = (unsigned int*)(nperm + 100000);    // 640,000
    unsigned int* stM = stN + 640000;                       // 640,000
    int* gcntN = (int*)(stM + 640000);                      // 256
    int* gcntM = gcntN + 256;                               // 256
    int* gcurN = gcntM + 256;                               // 256
    int* gcurM = gcurN + 256;                               // 256
    int* dcnt  = gcurM + 256;                               // 64
    int* dcur  = dcnt + 64;                                 // 64
    int* coffN = dcur + 64;                                 // 256 (197 used)
    int* coffM = coffN + 256;                               // 256 (158 used)

    const float scale = 0.08838834764831843f;  // 1/sqrt(128)
    const int nchunk = (E + 1023) / 1024;      // 625

    // -------- precompute + zeroing (runs first; independent of CSR) --------
    prep_a<<<142, 256, 0, stream>>>(W1, b1, W2, b2, W3, b3, W4, b4, W5, b5, Wc,
                                    W2T, W4T, b12v, w1b2, s12, b54v, w5b4, s54,
                                    W3c, b3c, zeros, gcntN);

    // -------- CSR build (both orientations) + degree hist --------
    coarse_hist<<<nchunk, 256, 0, stream>>>(nd, he, gcntN, gcntM, E);
    coarse_scan<<<2, 256, 0, stream>>>(gcntN, gcntM, coffN, coffM, E);
    part_scatter<<<nchunk, 256, 0, stream>>>(nd, he, coffN, coffM,
                                             gcurN, gcurM, stN, stM, E);
    bucket_build<<<NB_N + NB_M, 256, 0, stream>>>(stN, stM, coffN, coffM,
                                                  nd_off, he_off, nd_adj, he_adj,
                                                  dcnt);
    deg_scan<<<1, 64, 0, stream>>>(dcnt, dcur);
    deg_scatter<<<(N + 255) / 256, 256, 0, stream>>>(nd_off, dcur, nperm, N);

    // -------- weight-product GEMMs --------
    gemm_pair<<<dim3(2, 2), 512, 0, stream>>>(W1, W2T, W12, W5, W4T, W54, zeros);
    gemm_trip<<<dim3(2, 4), 512, 0, stream>>>(Wfl, bfl, W54, b54v, W6, b6, W12, b12v,
                                              w1b2, s12, w5b4, s54,
                                              Wk, Wv, Wq, bk, bv, bq,
                                              u_c, u_k, t_c, t_k, zeros);

    // -------- M-row dense layer + dots (y==6) --------
    gemm_m<<<dim3((M + 31) / 32, 7), 256, 0, stream>>>(
        efeat, Wk, bk, Wv, bv, Wq, bq, u_c, t_c, u_k, t_k, c_e, ck,
        (unsigned short*)kv_bf, qt_e, M);

    // -------- stage 1: hyperedge -> node --------
    attn_s1<<<(N * 16 + 255) / 256, 256, 0, stream>>>(
        vfeat, kv_bf, ck, nd_off, nd_adj, nperm, fv_bf, N, scale);

    // -------- stage 2: node -> hyperedge (head fused) --------
    attn_s2<<<M, 256, 0, stream>>>(qt_e, c_e, fv_bf, he_off, he_adj,
                                   W3c, b3c, bc, out, scale);
}

// Round 14
// 193.032 us; speedup vs baseline: 1.1173x; 1.1173x over previous
//
#include <hip/hip_runtime.h>
#include <hip/hip_bf16.h>
#include <math.h>

// ---------------------------------------------------------------------------
// Seq_HyGAN round 14: revert r13 regressions, keep fusions.
//  * attn_s1 back to 2-edge pipeline (r13 quad: VGPR 56, occ 34% -> worse).
//  * CSR chunks back to 4096 (1024 caused staging write amplification).
//  * deg_scan launch removed: deg_scatter recomputes the 64-bin scan locally.
//  * kept: head fused into attn_s2, dotc2 folded into gemm_m, prep_a zeroing.
//  11 launches.
// ---------------------------------------------------------------------------

#define HY_M 10000
#define HY_N 100000
#define HY_E 640000

#define SH_N 9              // node bucket width 512
#define NB_N 196            // ceil(100000/512)
#define SH_M 6              // hedge bucket width 64
#define NB_M 157            // ceil(10000/64)

typedef float        f32x4 __attribute__((ext_vector_type(4)));
typedef unsigned int u32x4 __attribute__((ext_vector_type(4)));

// ---- bf16 helpers (manual, RN) ----
__device__ __forceinline__ unsigned int f2bf(float x) {
    unsigned int u = __float_as_uint(x);
    return (u + 0x7fffu + ((u >> 16) & 1u)) >> 16;
}
__device__ __forceinline__ float2 bf2x2(unsigned int w) {
    float lo = __uint_as_float(w << 16);
    float hi = __uint_as_float(w & 0xffff0000u);
    return make_float2(lo, hi);
}
__device__ __forceinline__ float dot8(uint4 kw, float4 qa, float4 qb) {
    float2 k0 = bf2x2(kw.x), k1 = bf2x2(kw.y), k2 = bf2x2(kw.z), k3 = bf2x2(kw.w);
    return k0.x * qa.x + k0.y * qa.y + k1.x * qa.z + k1.y * qa.w
         + k2.x * qb.x + k2.y * qb.y + k3.x * qb.z + k3.y * qb.w;
}
__device__ __forceinline__ void unpack8(uint4 vw, float (&vf)[8]) {
    float2 v0 = bf2x2(vw.x), v1 = bf2x2(vw.y), v2 = bf2x2(vw.z), v3 = bf2x2(vw.w);
    vf[0] = v0.x; vf[1] = v0.y; vf[2] = v1.x; vf[3] = v1.y;
    vf[4] = v2.x; vf[5] = v2.y; vf[6] = v3.x; vf[7] = v3.y;
}
__device__ __forceinline__ float red16(float d) {
    d += __shfl_xor(d, 8); d += __shfl_xor(d, 4);
    d += __shfl_xor(d, 2); d += __shfl_xor(d, 1);
    return d;
}

// ---------------- CSR build: bucketed counting sort (4096-edge chunks) ------
__launch_bounds__(256)
__global__ void coarse_hist(const int* __restrict__ nd, const int* __restrict__ he,
                            int* __restrict__ gcntN, int* __restrict__ gcntM, int E) {
    __shared__ int hN[256], hM[256];
    const int t = threadIdx.x;
    hN[t] = 0; hM[t] = 0;
    __syncthreads();
    const int base = blockIdx.x * 4096;
    for (int i = t; i < 4096; i += 256) {
        int e = base + i;
        if (e < E) {
            atomicAdd(&hN[nd[e] >> SH_N], 1);
            atomicAdd(&hM[he[e] >> SH_M], 1);
        }
    }
    __syncthreads();
    if (hN[t]) atomicAdd(&gcntN[t], hN[t]);
    if (hM[t]) atomicAdd(&gcntM[t], hM[t]);
}

__global__ void coarse_scan(const int* __restrict__ gcntN, const int* __restrict__ gcntM,
                            int* __restrict__ coffN, int* __restrict__ coffM, int E) {
    __shared__ int s[256];
    const int* g = blockIdx.x ? gcntM : gcntN;
    int* o = blockIdx.x ? coffM : coffN;
    const int nb = blockIdx.x ? NB_M : NB_N;
    const int t = threadIdx.x;
    int v = (t < nb) ? g[t] : 0;
    int orig = v;
    s[t] = v; __syncthreads();
    for (int off = 1; off < 256; off <<= 1) {
        int x = (t >= off) ? s[t - off] : 0;
        __syncthreads(); s[t] += x; __syncthreads();
    }
    if (t < nb) o[t] = s[t] - orig;
    if (t == 0) o[nb] = E;
}

__launch_bounds__(256)
__global__ void part_scatter(const int* __restrict__ nd, const int* __restrict__ he,
                             const int* __restrict__ coffN, const int* __restrict__ coffM,
                             int* __restrict__ gcurN, int* __restrict__ gcurM,
                             unsigned int* __restrict__ stN, unsigned int* __restrict__ stM,
                             int E) {
    __shared__ int hN[256], hM[256];
    const int t = threadIdx.x;
    hN[t] = 0; hM[t] = 0;
    __syncthreads();
    const int base = blockIdx.x * 4096;
    for (int i = t; i < 4096; i += 256) {
        int e = base + i;
        if (e < E) {
            atomicAdd(&hN[nd[e] >> SH_N], 1);
            atomicAdd(&hM[he[e] >> SH_M], 1);
        }
    }
    __syncthreads();
    int cN = hN[t], cM = hM[t];
    __syncthreads();
    if (cN) hN[t] = coffN[t] + atomicAdd(&gcurN[t], cN);
    if (cM) hM[t] = coffM[t] + atomicAdd(&gcurM[t], cM);
    __syncthreads();
    for (int i = t; i < 4096; i += 256) {
        int e = base + i;
        if (e < E) {
            int d = nd[e], h = he[e];
            int pN = atomicAdd(&hN[d >> SH_N], 1);
            stN[pN] = ((unsigned int)(d & 511) << 14) | (unsigned int)h;
            int pM = atomicAdd(&hM[h >> SH_M], 1);
            stM[pM] = ((unsigned int)(h & 63) << 17) | (unsigned int)d;
        }
    }
}

// + folded node-degree histogram (feeds nperm build)
__launch_bounds__(256)
__global__ void bucket_build(const unsigned int* __restrict__ stN,
                             const unsigned int* __restrict__ stM,
                             const int* __restrict__ coffN, const int* __restrict__ coffM,
                             int* __restrict__ nd_off, int* __restrict__ he_off,
                             int* __restrict__ nd_adj, int* __restrict__ he_adj,
                             int* __restrict__ dcntg) {
    __shared__ int cnt[512];
    __shared__ int cur[512];
    __shared__ int ps[256];
    __shared__ int dh[64];
    int b = blockIdx.x;
    const int t = threadIdx.x;
    const unsigned int* st; const int* coff; int* offout; int* adj;
    int dmin, dcnt2, sshift; unsigned int smask; int ntot;
    const bool isN = b < NB_N;
    if (isN) {
        st = stN; coff = coffN; offout = nd_off; adj = nd_adj;
        dmin = b << SH_N; dcnt2 = min(512, HY_N - dmin);
        sshift = 14; smask = 0x3FFFu; ntot = HY_N;
    } else {
        b -= NB_N;
        st = stM; coff = coffM; offout = he_off; adj = he_adj;
        dmin = b << SH_M; dcnt2 = min(64, HY_M - dmin);
        sshift = 17; smask = 0x1FFFFu; ntot = HY_M;
    }
    const int cbase = coff[b], cend = coff[b + 1];
    cnt[t] = 0; cnt[t + 256] = 0;
    if (t < 64) dh[t] = 0;
    __syncthreads();
    for (int k = cbase + t; k < cend; k += 256)
        atomicAdd(&cnt[st[k] >> sshift], 1);
    __syncthreads();
    int a0 = cnt[2 * t], a1 = cnt[2 * t + 1];
    int pair = a0 + a1;
    ps[t] = pair;
    __syncthreads();
    for (int off = 1; off < 256; off <<= 1) {
        int x = (t >= off) ? ps[t - off] : 0;
        __syncthreads(); ps[t] += x; __syncthreads();
    }
    int excl = ps[t] - pair;
    cur[2 * t]     = cbase + excl;
    cur[2 * t + 1] = cbase + excl + a0;
    __syncthreads();
    for (int i = t; i < dcnt2; i += 256) offout[dmin + i] = cur[i];
    if (t == 0 && dmin + dcnt2 == ntot) offout[ntot] = cend;
    if (isN) {
        for (int i = t; i < dcnt2; i += 256)
            atomicAdd(&dh[min(cnt[i], 63)], 1);
    }
    __syncthreads();
    if (isN && t < 64 && dh[t]) atomicAdd(&dcntg[t], dh[t]);
    for (int k = cbase + t; k < cend; k += 256) {
        unsigned int w = st[k];
        int pos = atomicAdd(&cur[w >> sshift], 1);
        adj[pos] = (int)(w & smask);
    }
}

// ---------------- degree-sorted node permutation (DESCENDING = LPT) ---------
// scan folded in: each block recomputes the 64-bin descending exclusive scan
// from dcnt (global gdcur is a zero-initialized cursor).
__launch_bounds__(256)
__global__ void deg_scatter(const int* __restrict__ off, const int* __restrict__ dcnt,
                            int* __restrict__ gdcur, int* __restrict__ nperm, int n) {
    __shared__ int h[64];
    __shared__ int basev[64];
    __shared__ int sbase[64];
    int t = threadIdx.x;
    if (t < 64) {                               // wave 0: descending scan
        int rt = 63 - t;
        int v = dcnt[rt];
        int s = v;
        for (int o = 1; o < 64; o <<= 1) {
            int x = __shfl_up(s, o, 64);
            if (t >= o) s += x;
        }
        sbase[rt] = s - v;                      // #nodes with degree > rt
        h[t] = 0;
    }
    __syncthreads();
    int i = blockIdx.x * blockDim.x + t;
    int bin = 0, lpos = 0;
    bool valid = i < n;
    if (valid) {
        bin = min(off[i + 1] - off[i], 63);
        lpos = atomicAdd(&h[bin], 1);
    }
    __syncthreads();
    if (t < 64 && h[t]) basev[t] = atomicAdd(&gdcur[t], h[t]);
    __syncthreads();
    if (valid) nperm[sbase[bin] + basev[bin] + lpos] = i;
}

// ---------------- f32 GEMM core for 128x128 weight products ----------------
__device__ __forceinline__ void gemm_accum(const float* __restrict__ A,
        const float* __restrict__ W, int nrows, float* wlds,
        float (&acc)[4][4], int row0) {
    const int tid = threadIdx.x;
    const int cg = tid & 31;
    for (int i = tid; i < 4096; i += 512)
        ((float4*)wlds)[i] = ((const float4*)W)[i];
    __syncthreads();
    const float4* A0 = (const float4*)(A + (size_t)min(row0 + 0, nrows - 1) * 128);
    const float4* A1 = (const float4*)(A + (size_t)min(row0 + 1, nrows - 1) * 128);
    const float4* A2 = (const float4*)(A + (size_t)min(row0 + 2, nrows - 1) * 128);
    const float4* A3 = (const float4*)(A + (size_t)min(row0 + 3, nrows - 1) * 128);
    #pragma unroll 2
    for (int kq = 0; kq < 32; ++kq) {
        float4 ar[4] = {A0[kq], A1[kq], A2[kq], A3[kq]};
        const float4* wk = (const float4*)(wlds + kq * 512);
        float4 wr[4] = {wk[cg], wk[32 + cg], wk[64 + cg], wk[96 + cg]};
        #pragma unroll
        for (int r = 0; r < 4; ++r) {
            float av[4] = {ar[r].x, ar[r].y, ar[r].z, ar[r].w};
            #pragma unroll
            for (int j = 0; j < 4; ++j) {
                float wv[4] = {wr[j].x, wr[j].y, wr[j].z, wr[j].w};
                #pragma unroll
                for (int c = 0; c < 4; ++c)
                    acc[r][c] = fmaf(av[j], wv[c], acc[r][c]);
            }
        }
    }
}

__device__ __forceinline__ void gemm_store_f32(const float* __restrict__ b,
        float* __restrict__ Cf, int nrows, float (&acc)[4][4], int row0) {
    const int cg = threadIdx.x & 31;
    const float4 bv = ((const float4*)b)[cg];
    #pragma unroll
    for (int r = 0; r < 4; ++r) {
        int gr = row0 + r;
        if (gr < nrows) {
            float4 o = {acc[r][0] + bv.x, acc[r][1] + bv.y,
                        acc[r][2] + bv.z, acc[r][3] + bv.w};
            ((float4*)(Cf + (size_t)gr * 128))[cg] = o;
        }
    }
}

// y=0: W12=W1@W2T ; y=1: W54=W5@W4T
__launch_bounds__(512)
__global__ void gemm_pair(const float* __restrict__ Aa, const float* __restrict__ Wa,
                          float* __restrict__ Ca,
                          const float* __restrict__ Ab, const float* __restrict__ Wb,
                          float* __restrict__ Cb2, const float* __restrict__ zb) {
    __shared__ __align__(16) float wlds[16384];
    const int rs = threadIdx.x >> 5;
    const int row0 = blockIdx.x * 64 + rs * 4;
    const float* A = blockIdx.y ? Ab : Aa;
    const float* W = blockIdx.y ? Wb : Wa;
    float* C = blockIdx.y ? Cb2 : Ca;
    float acc[4][4] = {};
    gemm_accum(A, W, 128, wlds, acc, row0);
    gemm_store_f32(zb, C, 128, acc, row0);
}

// y=0..2: Wk/Wv/Wq = Wfl @ {W54,W6,W12} ; y=3,x=0: prep_fold
__launch_bounds__(512)
__global__ void gemm_trip(const float* __restrict__ Wfl, const float* __restrict__ bfl,
        const float* __restrict__ W54, const float* __restrict__ b54v,
        const float* __restrict__ W6, const float* __restrict__ b6,
        const float* __restrict__ W12, const float* __restrict__ b12v,
        const float* __restrict__ w1b2, const float* __restrict__ s12,
        const float* __restrict__ w5b4, const float* __restrict__ s54,
        float* __restrict__ Wk, float* __restrict__ Wv, float* __restrict__ Wq,
        float* __restrict__ bk, float* __restrict__ bv, float* __restrict__ bq,
        float* __restrict__ u_c, float* __restrict__ u_k,
        float* __restrict__ t_c, float* __restrict__ t_k,
        const float* __restrict__ zb) {
    __shared__ __align__(16) float wlds[16384];
    const int y = blockIdx.y;
    if (y == 3) {
        if (blockIdx.x != 0) return;
        int t = threadIdx.x;
        if (t < 128) {
            float a1 = 0.f, a2 = 0.f, a3 = 0.f;
            for (int j = 0; j < 128; ++j) {
                float f = bfl[j];
                a1 += f * W54[j * 128 + t];
                a2 += f * W6[j * 128 + t];
                a3 += f * W12[j * 128 + t];
            }
            bk[t] = a1 + b54v[t];
            bv[t] = a2 + b6[t];
            bq[t] = a3 + b12v[t];
        } else if (t < 256) {
            int k = t - 128;
            float a1 = 0.f, a2 = 0.f;
            for (int j = 0; j < 128; ++j) {
                float f = Wfl[k * 128 + j];
                a1 += f * w1b2[j];
                a2 += f * w5b4[j];
            }
            u_c[k] = a1;
            u_k[k] = a2;
        }
        if (t == 0) {
            float a1 = 0.f, a2 = 0.f;
            for (int j = 0; j < 128; ++j) {
                a1 += bfl[j] * w1b2[j];
                a2 += bfl[j] * w5b4[j];
            }
            *t_c = a1 + *s12;
            *t_k = a2 + *s54;
        }
        return;
    }
    const int rs = threadIdx.x >> 5;
    const int row0 = blockIdx.x * 64 + rs * 4;
    const float* W = y == 0 ? W54 : (y == 1 ? W6 : W12);
    float* C = y == 0 ? Wk : (y == 1 ? Wv : Wq);
    float acc[4][4] = {};
    gemm_accum(Wfl, W, 128, wlds, acc, row0);
    gemm_store_f32(zb, C, 128, acc, row0);
}

// ---------------- main M-row batched GEMM + dots (y==6) ----------------
__launch_bounds__(256)
__global__ void gemm_m(const float* __restrict__ A,
        const float* __restrict__ Wk, const float* __restrict__ bk,
        const float* __restrict__ Wv, const float* __restrict__ bvv,
        const float* __restrict__ Wq, const float* __restrict__ bq,
        const float* __restrict__ u_c, const float* __restrict__ t_c,
        const float* __restrict__ u_k, const float* __restrict__ t_k,
        float* __restrict__ c_e, float* __restrict__ ck,
        unsigned short* __restrict__ kv, float* __restrict__ qt, int nrows) {
    __shared__ __align__(16) float wlds[128 * 64];
    const int tid = threadIdx.x;
    if (blockIdx.y == 6) {                 // dotc2 rows
        const int w = tid >> 6, lane = tid & 63;
        float2 a1 = ((const float2*)u_c)[lane];
        float2 a2 = ((const float2*)u_k)[lane];
        for (int it = 0; it < 8; ++it) {
            int row = blockIdx.x * 32 + it * 4 + w;
            if (row < nrows) {
                float2 r = ((const float2*)(A + (size_t)row * 128))[lane];
                float d1 = r.x * a1.x + r.y * a1.y;
                float d2 = r.x * a2.x + r.y * a2.y;
                #pragma unroll
                for (int o = 32; o; o >>= 1) {
                    d1 += __shfl_xor(d1, o, 64);
                    d2 += __shfl_xor(d2, o, 64);
                }
                if (lane == 0) { c_e[row] = d1 + *t_c; ck[row] = d2 + *t_k; }
            }
        }
        return;
    }
    const int mat = blockIdx.y >> 1;
    const int half = blockIdx.y & 1;
    const float* W = mat == 0 ? Wk : (mat == 1 ? Wv : Wq);
    const float* bb = mat == 0 ? bk : (mat == 1 ? bvv : bq);
    const float4* W4 = (const float4*)W;
    float4* wl4 = (float4*)wlds;
    for (int i = tid; i < 2048; i += 256)
        wl4[i] = W4[(i >> 4) * 32 + half * 16 + (i & 15)];
    __syncthreads();
    const int cg = tid & 15;
    const int rs = tid >> 4;
    const int row0 = blockIdx.x * 32 + rs * 2;
    const float4* A0 = (const float4*)(A + (size_t)min(row0, nrows - 1) * 128);
    const float4* A1 = (const float4*)(A + (size_t)min(row0 + 1, nrows - 1) * 128);
    float acc[2][4] = {};
    #pragma unroll 4
    for (int kq = 0; kq < 32; ++kq) {
        float4 a0 = A0[kq], a1 = A1[kq];
        float av0[4] = {a0.x, a0.y, a0.z, a0.w};
        float av1[4] = {a1.x, a1.y, a1.z, a1.w};
        #pragma unroll
        for (int jj = 0; jj < 4; ++jj) {
            float4 w4 = wl4[(4 * kq + jj) * 16 + cg];
            float wv4[4] = {w4.x, w4.y, w4.z, w4.w};
            #pragma unroll
            for (int c = 0; c < 4; ++c) {
                acc[0][c] = fmaf(av0[jj], wv4[c], acc[0][c]);
                acc[1][c] = fmaf(av1[jj], wv4[c], acc[1][c]);
            }
        }
    }
    const float4 bv4 = ((const float4*)bb)[half * 16 + cg];
    #pragma unroll
    for (int r = 0; r < 2; ++r) {
        int gr = row0 + r;
        if (gr < nrows) {
            float o0 = acc[r][0] + bv4.x, o1 = acc[r][1] + bv4.y;
            float o2 = acc[r][2] + bv4.z, o3 = acc[r][3] + bv4.w;
            if (mat == 2) {
                float4 o = {o0, o1, o2, o3};
                ((float4*)(qt + (size_t)gr * 128))[half * 16 + cg] = o;
            } else {
                uint2 pk;
                pk.x = f2bf(o0) | (f2bf(o1) << 16);
                pk.y = f2bf(o2) | (f2bf(o3) << 16);
                *(uint2*)(kv + (size_t)gr * 256 + mat * 128 + half * 64 + cg * 4) = pk;
            }
        }
    }
}

// ---------------- fused precompute kernel (142 blocks, runs FIRST) ----------
__device__ __forceinline__ void prep_vecs_body(const float* WX, const float* WY,
        const float* bX, const float* bY, float* bXY, float* wXbY, float* sXY, int t) {
    if (t < 128) {
        float acc = 0.f;
        for (int j = 0; j < 128; ++j) acc += WY[t * 128 + j] * bX[j];
        bXY[t] = acc;
    } else {
        int k = t - 128;
        float acc = 0.f;
        for (int j = 0; j < 128; ++j) acc += WX[k * 128 + j] * bY[j];
        wXbY[k] = acc;
    }
    if (t == 0) {
        float acc = 0.f;
        for (int j = 0; j < 128; ++j) acc += bX[j] * bY[j];
        *sXY = acc;
    }
}

__global__ void prep_a(const float* __restrict__ W1, const float* __restrict__ b1,
                       const float* __restrict__ W2, const float* __restrict__ b2,
                       const float* __restrict__ W3, const float* __restrict__ b3,
                       const float* __restrict__ W4, const float* __restrict__ b4,
                       const float* __restrict__ W5, const float* __restrict__ b5,
                       const float* __restrict__ Wc,
                       float* __restrict__ W2T, float* __restrict__ W4T,
                       float* __restrict__ b12v, float* __restrict__ w1b2,
                       float* __restrict__ s12,
                       float* __restrict__ b54v, float* __restrict__ w5b4,
                       float* __restrict__ s54,
                       float* __restrict__ W3c, float* __restrict__ b3c,
                       float* __restrict__ zeros, int* __restrict__ zint) {
    const int x = blockIdx.x, t = threadIdx.x;
    if (x < 64) {
        int i = x * 256 + t;
        W2T[(i & 127) * 128 + (i >> 7)] = W2[i];
    } else if (x < 128) {
        int i = (x - 64) * 256 + t;
        W4T[(i & 127) * 128 + (i >> 7)] = W4[i];
    } else if (x == 128) {
        prep_vecs_body(W1, W2, b1, b2, b12v, w1b2, s12, t);
    } else if (x == 129) {
        prep_vecs_body(W5, W4, b5, b4, b54v, w5b4, s54, t);
    } else if (x < 136) {
        int i = (x - 130) * 256 + t;
        if (i < 1280) {
            int k = i / 10, c = i % 10;
            float acc = 0.f;
            for (int j = 0; j < 128; ++j) acc += W3[k * 128 + j] * Wc[j * 10 + c];
            W3c[i] = acc;
        } else if (i < 1290) {
            int c = i - 1280;
            float acc = 0.f;
            for (int j = 0; j < 128; ++j) acc += b3[j] * Wc[j * 10 + c];
            b3c[c] = acc;
        }
    } else if (x == 136) {
        if (t < 128) zeros[t] = 0.f;
    } else {                                   // x = 137..141: zero 1152 ints
        int i = (x - 137) * 256 + t;
        if (i < 1152) zint[i] = 0;
    }
}

// ---------------- stage 1: hyperedge -> node (2-edge pipeline) --------------
__launch_bounds__(256)
__global__ void attn_s1(const float* __restrict__ vf,          // N x 128 f32
                        const unsigned int* __restrict__ kv,   // M x 128 words (kt|v)
                        const float* __restrict__ ck,          // M
                        const int* __restrict__ off, const int* __restrict__ adj,
                        const int* __restrict__ nperm,
                        unsigned int* __restrict__ fv,         // N x 64 words
                        int nseg, float scale) {
    int slot = (blockIdx.x * blockDim.x + threadIdx.x) >> 4;
    int j = threadIdx.x & 15;
    if (slot >= nseg) return;
    int seg = nperm[slot];
    int beg = off[seg], end = off[seg + 1];
    const f32x4* qp = (const f32x4*)(vf + (size_t)seg * 128 + 8 * j);
    f32x4 qa4 = __builtin_nontemporal_load(qp);
    f32x4 qb4 = __builtin_nontemporal_load(qp + 1);
    float4 qa = {qa4.x, qa4.y, qa4.z, qa4.w};
    float4 qb = {qb4.x, qb4.y, qb4.z, qb4.w};
    float m = -INFINITY, l = 0.f;
    float a[8] = {};
    int i = beg;
    const int cnt = end - beg;
    if (cnt >= 2) {
        int s0 = adj[i], s1 = adj[i + 1];
        uint4 kw0 = ((const uint4*)(kv + (size_t)s0 * 128))[j];
        uint4 vw0 = ((const uint4*)(kv + (size_t)s0 * 128 + 64))[j];
        float c0 = ck[s0];
        uint4 kw1 = ((const uint4*)(kv + (size_t)s1 * 128))[j];
        uint4 vw1 = ((const uint4*)(kv + (size_t)s1 * 128 + 64))[j];
        float c1 = ck[s1];
        for (; i + 1 < end; i += 2) {
            uint4 ka = kw0, va = vw0, kb = kw1, vb = vw1;
            float ca = c0, cb = c1;
            if (i + 3 < end) {                     // prefetch next pair
                int t0 = adj[i + 2], t1 = adj[i + 3];
                kw0 = ((const uint4*)(kv + (size_t)t0 * 128))[j];
                vw0 = ((const uint4*)(kv + (size_t)t0 * 128 + 64))[j];
                c0 = ck[t0];
                kw1 = ((const uint4*)(kv + (size_t)t1 * 128))[j];
                vw1 = ((const uint4*)(kv + (size_t)t1 * 128 + 64))[j];
                c1 = ck[t1];
            } else if (i + 2 < end) {              // prefetch odd tail
                int t0 = adj[i + 2];
                kw0 = ((const uint4*)(kv + (size_t)t0 * 128))[j];
                vw0 = ((const uint4*)(kv + (size_t)t0 * 128 + 64))[j];
                c0 = ck[t0];
            }
            float d1 = dot8(ka, qa, qb);
            float d2 = dot8(kb, qa, qb);
            d1 += __shfl_xor(d1, 8); d2 += __shfl_xor(d2, 8);
            d1 += __shfl_xor(d1, 4); d2 += __shfl_xor(d2, 4);
            d1 += __shfl_xor(d1, 2); d2 += __shfl_xor(d2, 2);
            d1 += __shfl_xor(d1, 1); d2 += __shfl_xor(d2, 1);
            d1 += ca; d2 += cb;
            d1 = (d1 >= 0.f ? d1 : 0.01f * d1) * scale;
            d2 = (d2 >= 0.f ? d2 : 0.01f * d2) * scale;
            float mn = fmaxf(fmaxf(m, d1), d2);
            float r  = __expf(m - mn);             // first pair: exp(-inf)=0
            float p1 = __expf(d1 - mn);
            float p2 = __expf(d2 - mn);
            l = l * r + p1 + p2;
            float v1[8], v2[8];
            unpack8(va, v1); unpack8(vb, v2);
            #pragma unroll
            for (int t = 0; t < 8; ++t)
                a[t] = fmaf(p2, v2[t], fmaf(p1, v1[t], a[t] * r));
            m = mn;
        }
        if (i < end) {                             // odd tail (prefetched slot 0)
            float d = dot8(kw0, qa, qb);
            d = red16(d);
            d += c0;
            d = (d >= 0.f ? d : 0.01f * d) * scale;
            float mn = fmaxf(m, d);
            float r = __expf(m - mn);
            float p = __expf(d - mn);
            l = l * r + p;
            float v1[8]; unpack8(vw0, v1);
            #pragma unroll
            for (int t = 0; t < 8; ++t)
                a[t] = fmaf(p, v1[t], a[t] * r);
            m = mn;
        }
    } else if (cnt == 1) {
        int s0 = adj[i];
        uint4 kw0 = ((const uint4*)(kv + (size_t)s0 * 128))[j];
        uint4 vw0 = ((const uint4*)(kv + (size_t)s0 * 128 + 64))[j];
        float d = dot8(kw0, qa, qb);
        d = red16(d);
        d += ck[s0];
        d = (d >= 0.f ? d : 0.01f * d) * scale;
        l = 1.f;
        float v1[8]; unpack8(vw0, v1);
        #pragma unroll
        for (int t = 0; t < 8; ++t) a[t] = v1[t];
    }
    float inv = (l > 0.f) ? 1.f / l : 0.f;
    u32x4 o;
    o.x = f2bf(a[0] * inv) | (f2bf(a[1] * inv) << 16);
    o.y = f2bf(a[2] * inv) | (f2bf(a[3] * inv) << 16);
    o.z = f2bf(a[4] * inv) | (f2bf(a[5] * inv) << 16);
    o.w = f2bf(a[6] * inv) | (f2bf(a[7] * inv) << 16);
    __builtin_nontemporal_store(o, (u32x4*)(fv + (size_t)seg * 64 + 4 * j));
}

// ---------------- stage 2: node -> hyperedge (fused head) -------------------
__launch_bounds__(256)
__global__ void attn_s2(const float* __restrict__ QT, const float* __restrict__ cvec,
                        const unsigned int* __restrict__ fv,
                        const int* __restrict__ off, const int* __restrict__ adj,
                        const float* __restrict__ W3c, const float* __restrict__ b3c,
                        const float* __restrict__ bc, float* __restrict__ out,
                        float scale) {
    __shared__ float sm[16], sl[16];
    __shared__ float sacc[16][16][9];
    const int seg = blockIdx.x;
    const int g = threadIdx.x >> 4;
    const int j = threadIdx.x & 15;
    const int beg = off[seg], end = off[seg + 1];
    const f32x4* qp = (const f32x4*)(QT + (size_t)seg * 128 + 8 * j);
    f32x4 qa4 = __builtin_nontemporal_load(qp);
    f32x4 qb4 = __builtin_nontemporal_load(qp + 1);
    float4 qa = {qa4.x, qa4.y, qa4.z, qa4.w};
    float4 qb = {qb4.x, qb4.y, qb4.z, qb4.w};
    const float cadd = cvec[seg];
    float m = -INFINITY, l = 0.f;
    float a[8] = {};
    int it = beg + g;
    if (it + 16 < end) {
        int s0 = adj[it], s1 = adj[it + 16];
        uint4 rw0 = ((const uint4*)(fv + (size_t)s0 * 64))[j];
        uint4 rw1 = ((const uint4*)(fv + (size_t)s1 * 64))[j];
        for (; it + 16 < end; it += 32) {
            uint4 ra = rw0, rb = rw1;
            if (it + 48 < end) {
                int t0 = adj[it + 32], t1 = adj[it + 48];
                rw0 = ((const uint4*)(fv + (size_t)t0 * 64))[j];
                rw1 = ((const uint4*)(fv + (size_t)t1 * 64))[j];
            } else if (it + 32 < end) {
                int t0 = adj[it + 32];
                rw0 = ((const uint4*)(fv + (size_t)t0 * 64))[j];
            }
            float v1[8], v2[8];
            unpack8(ra, v1); unpack8(rb, v2);
            float d1 = v1[0] * qa.x + v1[1] * qa.y + v1[2] * qa.z + v1[3] * qa.w
                     + v1[4] * qb.x + v1[5] * qb.y + v1[6] * qb.z + v1[7] * qb.w;
            float d2 = v2[0] * qa.x + v2[1] * qa.y + v2[2] * qa.z + v2[3] * qa.w
                     + v2[4] * qb.x + v2[5] * qb.y + v2[6] * qb.z + v2[7] * qb.w;
            #pragma unroll
            for (int o = 8; o; o >>= 1) { d1 += __shfl_xor(d1, o); d2 += __shfl_xor(d2, o); }
            d1 += cadd; d2 += cadd;
            d1 = (d1 >= 0.f ? d1 : 0.01f * d1) * scale;
            d2 = (d2 >= 0.f ? d2 : 0.01f * d2) * scale;
            float mn = fmaxf(fmaxf(m, d1), d2);
            float r  = __expf(m - mn);
            float p1 = __expf(d1 - mn);
            float p2 = __expf(d2 - mn);
            l = l * r + p1 + p2;
            #pragma unroll
            for (int t = 0; t < 8; ++t)
                a[t] = fmaf(p2, v2[t], fmaf(p1, v1[t], a[t] * r));
            m = mn;
        }
        if (it < end) {
            float v1[8]; unpack8(rw0, v1);
            float d = v1[0] * qa.x + v1[1] * qa.y + v1[2] * qa.z + v1[3] * qa.w
                    + v1[4] * qb.x + v1[5] * qb.y + v1[6] * qb.z + v1[7] * qb.w;
            d = red16(d);
            d += cadd;
            d = (d >= 0.f ? d : 0.01f * d) * scale;
            float mn = fmaxf(m, d);
            float r = __expf(m - mn);
            float p = __expf(d - mn);
            l = l * r + p;
            #pragma unroll
            for (int t = 0; t < 8; ++t) a[t] = fmaf(p, v1[t], a[t] * r);
            m = mn;
        }
    } else if (it < end) {
        int s0 = adj[it];
        uint4 rw0 = ((const uint4*)(fv + (size_t)s0 * 64))[j];
        float v1[8]; unpack8(rw0, v1);
        float d = v1[0] * qa.x + v1[1] * qa.y + v1[2] * qa.z + v1[3] * qa.w
                + v1[4] * qb.x + v1[5] * qb.y + v1[6] * qb.z + v1[7] * qb.w;
        d = red16(d);
        d += cadd;
        d = (d >= 0.f ? d : 0.01f * d) * scale;
        m = d; l = 1.f;
        #pragma unroll
        for (int t = 0; t < 8; ++t) a[t] = v1[t];
    }
    if (j == 0) { sm[g] = m; sl[g] = l; }
    #pragma unroll
    for (int t = 0; t < 8; ++t) sacc[g][j][t] = a[t];
    __syncthreads();
    if (threadIdx.x < 16) {                    // lanes 0-15 of wave 0
        const int t16 = threadIdx.x;
        float M2 = -INFINITY;
        #pragma unroll 4
        for (int gg = 0; gg < 16; ++gg) if (sl[gg] > 0.f) M2 = fmaxf(M2, sm[gg]);
        float L = 0.f;
        float acc[8] = {};
        #pragma unroll 4
        for (int gg = 0; gg < 16; ++gg) {
            float f = (sl[gg] > 0.f) ? __expf(sm[gg] - M2) : 0.f;
            L += f * sl[gg];
            #pragma unroll
            for (int t = 0; t < 8; ++t) acc[t] += f * sacc[gg][t16][t];
        }
        float inv = (L > 0.f) ? 1.f / L : 0.f;
        float fl  = (L > 0.f) ? 1.f : 0.f;
        #pragma unroll
        for (int t = 0; t < 8; ++t) acc[t] *= inv;
        float pp[10];
        #pragma unroll
        for (int c = 0; c < 10; ++c) {
            float s = 0.f;
            #pragma unroll
            for (int t = 0; t < 8; ++t)
                s = fmaf(acc[t], W3c[(8 * t16 + t) * 10 + c], s);
            pp[c] = s;
        }
        #pragma unroll
        for (int o = 8; o; o >>= 1) {
            #pragma unroll
            for (int c = 0; c < 10; ++c) pp[c] += __shfl_xor(pp[c], o);
        }
        if (t16 == 0) {
            #pragma unroll
            for (int c = 0; c < 10; ++c)
                out[(size_t)seg * 10 + c] = pp[c] + fl * b3c[c] + bc[c];
        }
    }
}

extern "C" void kernel_launch(void* const* d_in, const int* in_sizes, int n_in,
                              void* d_out, int out_size, void* d_ws, size_t ws_size,
                              hipStream_t stream) {
    const float* vfeat = (const float*)d_in[0];
    const float* efeat = (const float*)d_in[1];
    const int*   he    = (const int*)d_in[2];
    const int*   nd    = (const int*)d_in[3];
    const float* Wfl = (const float*)d_in[6],  *bfl = (const float*)d_in[7];
    const float* W1  = (const float*)d_in[8],  *b1  = (const float*)d_in[9];
    const float* W2  = (const float*)d_in[10], *b2  = (const float*)d_in[11];
    const float* W3  = (const float*)d_in[12], *b3  = (const float*)d_in[13];
    const float* W4  = (const float*)d_in[14], *b4  = (const float*)d_in[15];
    const float* W5  = (const float*)d_in[16], *b5  = (const float*)d_in[17];
    const float* W6  = (const float*)d_in[18], *b6  = (const float*)d_in[19];
    const float* Wc  = (const float*)d_in[20], *bc  = (const float*)d_in[21];
    float* out = (float*)d_out;
    float* ws  = (float*)d_ws;

    const int M = HY_M, N = HY_N, E = HY_E;

    // -------- workspace layout (float units) --------
    float* qt_e  = ws + 0;         // 1,280,000
    float* c_e   = ws + 1280000;   // 10,000
    float* ck    = ws + 1290000;   // 10,000
    float* W2T   = ws + 1300000;   // 16384
    float* W4T   = ws + 1316384;   // 16384
    float* W12   = ws + 1332768;   // 16384
    float* W54   = ws + 1349152;   // 16384
    float* Wk    = ws + 1365536;   // 16384
    float* Wv    = ws + 1381920;   // 16384
    float* Wq    = ws + 1398304;   // 16384
    float* W3c   = ws + 1414688;   // 1280
    float* b3c   = ws + 1415968;   // 16
    float* b12v  = ws + 1415984;   // 128
    float* w1b2  = ws + 1416112;   // 128
    float* s12   = ws + 1416240;   // 4
    float* b54v  = ws + 1416244;   // 128
    float* w5b4  = ws + 1416372;   // 128
    float* s54   = ws + 1416500;   // 4
    float* bk    = ws + 1416504;   // 128
    float* bv    = ws + 1416632;   // 128
    float* bq    = ws + 1416760;   // 128
    float* u_c   = ws + 1416888;   // 128
    float* u_k   = ws + 1417016;   // 128
    float* t_c   = ws + 1417144;   // 4
    float* t_k   = ws + 1417148;   // 4
    float* zeros = ws + 1417152;   // 128 (ends 1417280)
    unsigned int* kv_bf = (unsigned int*)(ws + 1417280);   // M*128 words
    unsigned int* fv_bf = kv_bf + (size_t)M * 128;         // N*64 words
    int* nd_off = (int*)(fv_bf + (size_t)N * 64);          // 100,001
    int* he_off = nd_off + 100001;                          // 10,001
    int* nd_adj = he_off + 10001;                           // 640,000
    int* he_adj = nd_adj + 640000;                          // 640,000
    int* nperm  = he_adj + 640000;                          // 100,000
    unsigned int* stN = (unsigned int*)(nperm + 100000);    // 640,000
    unsigned int* stM = stN + 640000;                       // 640,000
    int* gcntN = (int*)(stM + 640000);                      // 256
    int* gcntM = gcntN + 256;                               // 256
    int* gcurN = gcntM + 256;                               // 256
    int* gcurM = gcurN + 256;                               // 256
    int* dcnt  = gcurM + 256;                               // 64
    int* gdcur = dcnt + 64;                                 // 64
    int* coffN = gdcur + 64;                                // 256 (197 used)
    int* coffM = coffN + 256;                               // 256 (158 used)

    const float scale = 0.08838834764831843f;  // 1/sqrt(128)
    const int nchunk = (E + 4095) / 4096;      // 157

    // -------- precompute + zeroing (runs first) --------
    prep_a<<<142, 256, 0, stream>>>(W1, b1, W2, b2, W3, b3, W4, b4, W5, b5, Wc,
                                    W2T, W4T, b12v, w1b2, s12, b54v, w5b4, s54,
                                    W3c, b3c, zeros, gcntN);

    // -------- CSR build (both orientations) + degree hist --------
    coarse_hist<<<nchunk, 256, 0, stream>>>(nd, he, gcntN, gcntM, E);
    coarse_scan<<<2, 256, 0, stream>>>(gcntN, gcntM, coffN, coffM, E);
    part_scatter<<<nchunk, 256, 0, stream>>>(nd, he, coffN, coffM,
                                             gcurN, gcurM, stN, stM, E);
    bucket_build<<<NB_N + NB_M, 256, 0, stream>>>(stN, stM, coffN, coffM,
                                                  nd_off, he_off, nd_adj, he_adj,
                                                  dcnt);
    deg_scatter<<<(N + 255) / 256, 256, 0, stream>>>(nd_off, dcnt, gdcur, nperm, N);

    // -------- weight-product GEMMs --------
    gemm_pair<<<dim3(2, 2), 512, 0, stream>>>(W1, W2T, W12, W5, W4T, W54, zeros);
    gemm_trip<<<dim3(2, 4), 512, 0, stream>>>(Wfl, bfl, W54, b54v, W6, b6, W12, b12v,
                                              w1b2, s12, w5b4, s54,
                                              Wk, Wv, Wq, bk, bv, bq,
                                              u_c, u_k, t_c, t_k, zeros);

    // -------- M-row dense layer + dots (y==6) --------
    gemm_m<<<dim3((M + 31) / 32, 7), 256, 0, stream>>>(
        efeat, Wk, bk, Wv, bv, Wq, bq, u_c, t_c, u_k, t_k, c_e, ck,
        (unsigned short*)kv_bf, qt_e, M);

    // -------- stage 1: hyperedge -> node --------
    attn_s1<<<(N * 16 + 255) / 256, 256, 0, stream>>>(
        vfeat, kv_bf, ck, nd_off, nd_adj, nperm, fv_bf, N, scale);

    // -------- stage 2: node -> hyperedge (head fused) --------
    attn_s2<<<M, 256, 0, stream>>>(qt_e, c_e, fv_bf, he_off, he_adj,
                                   W3c, b3c, bc, out, scale);
}

// Round 15
// 189.903 us; speedup vs baseline: 1.1357x; 1.0165x over previous
//
#include <hip/hip_runtime.h>
#include <hip/hip_bf16.h>
#include <math.h>

// ---------------------------------------------------------------------------
// Seq_HyGAN round 15: attn_s2 polish.
//  * qt_e stored bf16 (fv-style 64-word rows): halves attn_s2 q stream.
//  * attn_s2 merge+head parallelized over 64 lanes (was 16-lane serial loop).
//  Everything else identical to round 14 (193us).
// ---------------------------------------------------------------------------

#define HY_M 10000
#define HY_N 100000
#define HY_E 640000

#define SH_N 9              // node bucket width 512
#define NB_N 196            // ceil(100000/512)
#define SH_M 6              // hedge bucket width 64
#define NB_M 157            // ceil(10000/64)

typedef float        f32x4 __attribute__((ext_vector_type(4)));
typedef unsigned int u32x4 __attribute__((ext_vector_type(4)));

// ---- bf16 helpers (manual, RN) ----
__device__ __forceinline__ unsigned int f2bf(float x) {
    unsigned int u = __float_as_uint(x);
    return (u + 0x7fffu + ((u >> 16) & 1u)) >> 16;
}
__device__ __forceinline__ float2 bf2x2(unsigned int w) {
    float lo = __uint_as_float(w << 16);
    float hi = __uint_as_float(w & 0xffff0000u);
    return make_float2(lo, hi);
}
__device__ __forceinline__ float dot8(uint4 kw, float4 qa, float4 qb) {
    float2 k0 = bf2x2(kw.x), k1 = bf2x2(kw.y), k2 = bf2x2(kw.z), k3 = bf2x2(kw.w);
    return k0.x * qa.x + k0.y * qa.y + k1.x * qa.z + k1.y * qa.w
         + k2.x * qb.x + k2.y * qb.y + k3.x * qb.z + k3.y * qb.w;
}
__device__ __forceinline__ void unpack8(uint4 vw, float (&vf)[8]) {
    float2 v0 = bf2x2(vw.x), v1 = bf2x2(vw.y), v2 = bf2x2(vw.z), v3 = bf2x2(vw.w);
    vf[0] = v0.x; vf[1] = v0.y; vf[2] = v1.x; vf[3] = v1.y;
    vf[4] = v2.x; vf[5] = v2.y; vf[6] = v3.x; vf[7] = v3.y;
}
__device__ __forceinline__ float red16(float d) {
    d += __shfl_xor(d, 8); d += __shfl_xor(d, 4);
    d += __shfl_xor(d, 2); d += __shfl_xor(d, 1);
    return d;
}

// ---------------- CSR build: bucketed counting sort (4096-edge chunks) ------
__launch_bounds__(256)
__global__ void coarse_hist(const int* __restrict__ nd, const int* __restrict__ he,
                            int* __restrict__ gcntN, int* __restrict__ gcntM, int E) {
    __shared__ int hN[256], hM[256];
    const int t = threadIdx.x;
    hN[t] = 0; hM[t] = 0;
    __syncthreads();
    const int base = blockIdx.x * 4096;
    for (int i = t; i < 4096; i += 256) {
        int e = base + i;
        if (e < E) {
            atomicAdd(&hN[nd[e] >> SH_N], 1);
            atomicAdd(&hM[he[e] >> SH_M], 1);
        }
    }
    __syncthreads();
    if (hN[t]) atomicAdd(&gcntN[t], hN[t]);
    if (hM[t]) atomicAdd(&gcntM[t], hM[t]);
}

__global__ void coarse_scan(const int* __restrict__ gcntN, const int* __restrict__ gcntM,
                            int* __restrict__ coffN, int* __restrict__ coffM, int E) {
    __shared__ int s[256];
    const int* g = blockIdx.x ? gcntM : gcntN;
    int* o = blockIdx.x ? coffM : coffN;
    const int nb = blockIdx.x ? NB_M : NB_N;
    const int t = threadIdx.x;
    int v = (t < nb) ? g[t] : 0;
    int orig = v;
    s[t] = v; __syncthreads();
    for (int off = 1; off < 256; off <<= 1) {
        int x = (t >= off) ? s[t - off] : 0;
        __syncthreads(); s[t] += x; __syncthreads();
    }
    if (t < nb) o[t] = s[t] - orig;
    if (t == 0) o[nb] = E;
}

__launch_bounds__(256)
__global__ void part_scatter(const int* __restrict__ nd, const int* __restrict__ he,
                             const int* __restrict__ coffN, const int* __restrict__ coffM,
                             int* __restrict__ gcurN, int* __restrict__ gcurM,
                             unsigned int* __restrict__ stN, unsigned int* __restrict__ stM,
                             int E) {
    __shared__ int hN[256], hM[256];
    const int t = threadIdx.x;
    hN[t] = 0; hM[t] = 0;
    __syncthreads();
    const int base = blockIdx.x * 4096;
    for (int i = t; i < 4096; i += 256) {
        int e = base + i;
        if (e < E) {
            atomicAdd(&hN[nd[e] >> SH_N], 1);
            atomicAdd(&hM[he[e] >> SH_M], 1);
        }
    }
    __syncthreads();
    int cN = hN[t], cM = hM[t];
    __syncthreads();
    if (cN) hN[t] = coffN[t] + atomicAdd(&gcurN[t], cN);
    if (cM) hM[t] = coffM[t] + atomicAdd(&gcurM[t], cM);
    __syncthreads();
    for (int i = t; i < 4096; i += 256) {
        int e = base + i;
        if (e < E) {
            int d = nd[e], h = he[e];
            int pN = atomicAdd(&hN[d >> SH_N], 1);
            stN[pN] = ((unsigned int)(d & 511) << 14) | (unsigned int)h;
            int pM = atomicAdd(&hM[h >> SH_M], 1);
            stM[pM] = ((unsigned int)(h & 63) << 17) | (unsigned int)d;
        }
    }
}

// + folded node-degree histogram (feeds nperm build)
__launch_bounds__(256)
__global__ void bucket_build(const unsigned int* __restrict__ stN,
                             const unsigned int* __restrict__ stM,
                             const int* __restrict__ coffN, const int* __restrict__ coffM,
                             int* __restrict__ nd_off, int* __restrict__ he_off,
                             int* __restrict__ nd_adj, int* __restrict__ he_adj,
                             int* __restrict__ dcntg) {
    __shared__ int cnt[512];
    __shared__ int cur[512];
    __shared__ int ps[256];
    __shared__ int dh[64];
    int b = blockIdx.x;
    const int t = threadIdx.x;
    const unsigned int* st; const int* coff; int* offout; int* adj;
    int dmin, dcnt2, sshift; unsigned int smask; int ntot;
    const bool isN = b < NB_N;
    if (isN) {
        st = stN; coff = coffN; offout = nd_off; adj = nd_adj;
        dmin = b << SH_N; dcnt2 = min(512, HY_N - dmin);
        sshift = 14; smask = 0x3FFFu; ntot = HY_N;
    } else {
        b -= NB_N;
        st = stM; coff = coffM; offout = he_off; adj = he_adj;
        dmin = b << SH_M; dcnt2 = min(64, HY_M - dmin);
        sshift = 17; smask = 0x1FFFFu; ntot = HY_M;
    }
    const int cbase = coff[b], cend = coff[b + 1];
    cnt[t] = 0; cnt[t + 256] = 0;
    if (t < 64) dh[t] = 0;
    __syncthreads();
    for (int k = cbase + t; k < cend; k += 256)
        atomicAdd(&cnt[st[k] >> sshift], 1);
    __syncthreads();
    int a0 = cnt[2 * t], a1 = cnt[2 * t + 1];
    int pair = a0 + a1;
    ps[t] = pair;
    __syncthreads();
    for (int off = 1; off < 256; off <<= 1) {
        int x = (t >= off) ? ps[t - off] : 0;
        __syncthreads(); ps[t] += x; __syncthreads();
    }
    int excl = ps[t] - pair;
    cur[2 * t]     = cbase + excl;
    cur[2 * t + 1] = cbase + excl + a0;
    __syncthreads();
    for (int i = t; i < dcnt2; i += 256) offout[dmin + i] = cur[i];
    if (t == 0 && dmin + dcnt2 == ntot) offout[ntot] = cend;
    if (isN) {
        for (int i = t; i < dcnt2; i += 256)
            atomicAdd(&dh[min(cnt[i], 63)], 1);
    }
    __syncthreads();
    if (isN && t < 64 && dh[t]) atomicAdd(&dcntg[t], dh[t]);
    for (int k = cbase + t; k < cend; k += 256) {
        unsigned int w = st[k];
        int pos = atomicAdd(&cur[w >> sshift], 1);
        adj[pos] = (int)(w & smask);
    }
}

// ---------------- degree-sorted node permutation (DESCENDING = LPT) ---------
__launch_bounds__(256)
__global__ void deg_scatter(const int* __restrict__ off, const int* __restrict__ dcnt,
                            int* __restrict__ gdcur, int* __restrict__ nperm, int n) {
    __shared__ int h[64];
    __shared__ int basev[64];
    __shared__ int sbase[64];
    int t = threadIdx.x;
    if (t < 64) {                               // wave 0: descending scan
        int rt = 63 - t;
        int v = dcnt[rt];
        int s = v;
        for (int o = 1; o < 64; o <<= 1) {
            int x = __shfl_up(s, o, 64);
            if (t >= o) s += x;
        }
        sbase[rt] = s - v;                      // #nodes with degree > rt
        h[t] = 0;
    }
    __syncthreads();
    int i = blockIdx.x * blockDim.x + t;
    int bin = 0, lpos = 0;
    bool valid = i < n;
    if (valid) {
        bin = min(off[i + 1] - off[i], 63);
        lpos = atomicAdd(&h[bin], 1);
    }
    __syncthreads();
    if (t < 64 && h[t]) basev[t] = atomicAdd(&gdcur[t], h[t]);
    __syncthreads();
    if (valid) nperm[sbase[bin] + basev[bin] + lpos] = i;
}

// ---------------- f32 GEMM core for 128x128 weight products ----------------
__device__ __forceinline__ void gemm_accum(const float* __restrict__ A,
        const float* __restrict__ W, int nrows, float* wlds,
        float (&acc)[4][4], int row0) {
    const int tid = threadIdx.x;
    const int cg = tid & 31;
    for (int i = tid; i < 4096; i += 512)
        ((float4*)wlds)[i] = ((const float4*)W)[i];
    __syncthreads();
    const float4* A0 = (const float4*)(A + (size_t)min(row0 + 0, nrows - 1) * 128);
    const float4* A1 = (const float4*)(A + (size_t)min(row0 + 1, nrows - 1) * 128);
    const float4* A2 = (const float4*)(A + (size_t)min(row0 + 2, nrows - 1) * 128);
    const float4* A3 = (const float4*)(A + (size_t)min(row0 + 3, nrows - 1) * 128);
    #pragma unroll 2
    for (int kq = 0; kq < 32; ++kq) {
        float4 ar[4] = {A0[kq], A1[kq], A2[kq], A3[kq]};
        const float4* wk = (const float4*)(wlds + kq * 512);
        float4 wr[4] = {wk[cg], wk[32 + cg], wk[64 + cg], wk[96 + cg]};
        #pragma unroll
        for (int r = 0; r < 4; ++r) {
            float av[4] = {ar[r].x, ar[r].y, ar[r].z, ar[r].w};
            #pragma unroll
            for (int j = 0; j < 4; ++j) {
                float wv[4] = {wr[j].x, wr[j].y, wr[j].z, wr[j].w};
                #pragma unroll
                for (int c = 0; c < 4; ++c)
                    acc[r][c] = fmaf(av[j], wv[c], acc[r][c]);
            }
        }
    }
}

__device__ __forceinline__ void gemm_store_f32(const float* __restrict__ b,
        float* __restrict__ Cf, int nrows, float (&acc)[4][4], int row0) {
    const int cg = threadIdx.x & 31;
    const float4 bv = ((const float4*)b)[cg];
    #pragma unroll
    for (int r = 0; r < 4; ++r) {
        int gr = row0 + r;
        if (gr < nrows) {
            float4 o = {acc[r][0] + bv.x, acc[r][1] + bv.y,
                        acc[r][2] + bv.z, acc[r][3] + bv.w};
            ((float4*)(Cf + (size_t)gr * 128))[cg] = o;
        }
    }
}

// y=0: W12=W1@W2T ; y=1: W54=W5@W4T
__launch_bounds__(512)
__global__ void gemm_pair(const float* __restrict__ Aa, const float* __restrict__ Wa,
                          float* __restrict__ Ca,
                          const float* __restrict__ Ab, const float* __restrict__ Wb,
                          float* __restrict__ Cb2, const float* __restrict__ zb) {
    __shared__ __align__(16) float wlds[16384];
    const int rs = threadIdx.x >> 5;
    const int row0 = blockIdx.x * 64 + rs * 4;
    const float* A = blockIdx.y ? Ab : Aa;
    const float* W = blockIdx.y ? Wb : Wa;
    float* C = blockIdx.y ? Cb2 : Ca;
    float acc[4][4] = {};
    gemm_accum(A, W, 128, wlds, acc, row0);
    gemm_store_f32(zb, C, 128, acc, row0);
}

// y=0..2: Wk/Wv/Wq = Wfl @ {W54,W6,W12} ; y=3,x=0: prep_fold
__launch_bounds__(512)
__global__ void gemm_trip(const float* __restrict__ Wfl, const float* __restrict__ bfl,
        const float* __restrict__ W54, const float* __restrict__ b54v,
        const float* __restrict__ W6, const float* __restrict__ b6,
        const float* __restrict__ W12, const float* __restrict__ b12v,
        const float* __restrict__ w1b2, const float* __restrict__ s12,
        const float* __restrict__ w5b4, const float* __restrict__ s54,
        float* __restrict__ Wk, float* __restrict__ Wv, float* __restrict__ Wq,
        float* __restrict__ bk, float* __restrict__ bv, float* __restrict__ bq,
        float* __restrict__ u_c, float* __restrict__ u_k,
        float* __restrict__ t_c, float* __restrict__ t_k,
        const float* __restrict__ zb) {
    __shared__ __align__(16) float wlds[16384];
    const int y = blockIdx.y;
    if (y == 3) {
        if (blockIdx.x != 0) return;
        int t = threadIdx.x;
        if (t < 128) {
            float a1 = 0.f, a2 = 0.f, a3 = 0.f;
            for (int j = 0; j < 128; ++j) {
                float f = bfl[j];
                a1 += f * W54[j * 128 + t];
                a2 += f * W6[j * 128 + t];
                a3 += f * W12[j * 128 + t];
            }
            bk[t] = a1 + b54v[t];
            bv[t] = a2 + b6[t];
            bq[t] = a3 + b12v[t];
        } else if (t < 256) {
            int k = t - 128;
            float a1 = 0.f, a2 = 0.f;
            for (int j = 0; j < 128; ++j) {
                float f = Wfl[k * 128 + j];
                a1 += f * w1b2[j];
                a2 += f * w5b4[j];
            }
            u_c[k] = a1;
            u_k[k] = a2;
        }
        if (t == 0) {
            float a1 = 0.f, a2 = 0.f;
            for (int j = 0; j < 128; ++j) {
                a1 += bfl[j] * w1b2[j];
                a2 += bfl[j] * w5b4[j];
            }
            *t_c = a1 + *s12;
            *t_k = a2 + *s54;
        }
        return;
    }
    const int rs = threadIdx.x >> 5;
    const int row0 = blockIdx.x * 64 + rs * 4;
    const float* W = y == 0 ? W54 : (y == 1 ? W6 : W12);
    float* C = y == 0 ? Wk : (y == 1 ? Wv : Wq);
    float acc[4][4] = {};
    gemm_accum(Wfl, W, 128, wlds, acc, row0);
    gemm_store_f32(zb, C, 128, acc, row0);
}

// ---------------- main M-row batched GEMM + dots (y==6) ----------------
// mat 0 -> kv k-half ; mat 1 -> kv v-half ; mat 2 -> qt (bf16, 64-word rows)
__launch_bounds__(256)
__global__ void gemm_m(const float* __restrict__ A,
        const float* __restrict__ Wk, const float* __restrict__ bk,
        const float* __restrict__ Wv, const float* __restrict__ bvv,
        const float* __restrict__ Wq, const float* __restrict__ bq,
        const float* __restrict__ u_c, const float* __restrict__ t_c,
        const float* __restrict__ u_k, const float* __restrict__ t_k,
        float* __restrict__ c_e, float* __restrict__ ck,
        unsigned short* __restrict__ kv, unsigned short* __restrict__ qtb, int nrows) {
    __shared__ __align__(16) float wlds[128 * 64];
    const int tid = threadIdx.x;
    if (blockIdx.y == 6) {                 // dotc2 rows
        const int w = tid >> 6, lane = tid & 63;
        float2 a1 = ((const float2*)u_c)[lane];
        float2 a2 = ((const float2*)u_k)[lane];
        for (int it = 0; it < 8; ++it) {
            int row = blockIdx.x * 32 + it * 4 + w;
            if (row < nrows) {
                float2 r = ((const float2*)(A + (size_t)row * 128))[lane];
                float d1 = r.x * a1.x + r.y * a1.y;
                float d2 = r.x * a2.x + r.y * a2.y;
                #pragma unroll
                for (int o = 32; o; o >>= 1) {
                    d1 += __shfl_xor(d1, o, 64);
                    d2 += __shfl_xor(d2, o, 64);
                }
                if (lane == 0) { c_e[row] = d1 + *t_c; ck[row] = d2 + *t_k; }
            }
        }
        return;
    }
    const int mat = blockIdx.y >> 1;
    const int half = blockIdx.y & 1;
    const float* W = mat == 0 ? Wk : (mat == 1 ? Wv : Wq);
    const float* bb = mat == 0 ? bk : (mat == 1 ? bvv : bq);
    const float4* W4 = (const float4*)W;
    float4* wl4 = (float4*)wlds;
    for (int i = tid; i < 2048; i += 256)
        wl4[i] = W4[(i >> 4) * 32 + half * 16 + (i & 15)];
    __syncthreads();
    const int cg = tid & 15;
    const int rs = tid >> 4;
    const int row0 = blockIdx.x * 32 + rs * 2;
    const float4* A0 = (const float4*)(A + (size_t)min(row0, nrows - 1) * 128);
    const float4* A1 = (const float4*)(A + (size_t)min(row0 + 1, nrows - 1) * 128);
    float acc[2][4] = {};
    #pragma unroll 4
    for (int kq = 0; kq < 32; ++kq) {
        float4 a0 = A0[kq], a1 = A1[kq];
        float av0[4] = {a0.x, a0.y, a0.z, a0.w};
        float av1[4] = {a1.x, a1.y, a1.z, a1.w};
        #pragma unroll
        for (int jj = 0; jj < 4; ++jj) {
            float4 w4 = wl4[(4 * kq + jj) * 16 + cg];
            float wv4[4] = {w4.x, w4.y, w4.z, w4.w};
            #pragma unroll
            for (int c = 0; c < 4; ++c) {
                acc[0][c] = fmaf(av0[jj], wv4[c], acc[0][c]);
                acc[1][c] = fmaf(av1[jj], wv4[c], acc[1][c]);
            }
        }
    }
    const float4 bv4 = ((const float4*)bb)[half * 16 + cg];
    #pragma unroll
    for (int r = 0; r < 2; ++r) {
        int gr = row0 + r;
        if (gr < nrows) {
            float o0 = acc[r][0] + bv4.x, o1 = acc[r][1] + bv4.y;
            float o2 = acc[r][2] + bv4.z, o3 = acc[r][3] + bv4.w;
            uint2 pk;
            pk.x = f2bf(o0) | (f2bf(o1) << 16);
            pk.y = f2bf(o2) | (f2bf(o3) << 16);
            if (mat == 2)
                *(uint2*)(qtb + (size_t)gr * 128 + half * 64 + cg * 4) = pk;
            else
                *(uint2*)(kv + (size_t)gr * 256 + mat * 128 + half * 64 + cg * 4) = pk;
        }
    }
}

// ---------------- fused precompute kernel (142 blocks, runs FIRST) ----------
__device__ __forceinline__ void prep_vecs_body(const float* WX, const float* WY,
        const float* bX, const float* bY, float* bXY, float* wXbY, float* sXY, int t) {
    if (t < 128) {
        float acc = 0.f;
        for (int j = 0; j < 128; ++j) acc += WY[t * 128 + j] * bX[j];
        bXY[t] = acc;
    } else {
        int k = t - 128;
        float acc = 0.f;
        for (int j = 0; j < 128; ++j) acc += WX[k * 128 + j] * bY[j];
        wXbY[k] = acc;
    }
    if (t == 0) {
        float acc = 0.f;
        for (int j = 0; j < 128; ++j) acc += bX[j] * bY[j];
        *sXY = acc;
    }
}

__global__ void prep_a(const float* __restrict__ W1, const float* __restrict__ b1,
                       const float* __restrict__ W2, const float* __restrict__ b2,
                       const float* __restrict__ W3, const float* __restrict__ b3,
                       const float* __restrict__ W4, const float* __restrict__ b4,
                       const float* __restrict__ W5, const float* __restrict__ b5,
                       const float* __restrict__ Wc,
                       float* __restrict__ W2T, float* __restrict__ W4T,
                       float* __restrict__ b12v, float* __restrict__ w1b2,
                       float* __restrict__ s12,
                       float* __restrict__ b54v, float* __restrict__ w5b4,
                       float* __restrict__ s54,
                       float* __restrict__ W3c, float* __restrict__ b3c,
                       float* __restrict__ zeros, int* __restrict__ zint) {
    const int x = blockIdx.x, t = threadIdx.x;
    if (x < 64) {
        int i = x * 256 + t;
        W2T[(i & 127) * 128 + (i >> 7)] = W2[i];
    } else if (x < 128) {
        int i = (x - 64) * 256 + t;
        W4T[(i & 127) * 128 + (i >> 7)] = W4[i];
    } else if (x == 128) {
        prep_vecs_body(W1, W2, b1, b2, b12v, w1b2, s12, t);
    } else if (x == 129) {
        prep_vecs_body(W5, W4, b5, b4, b54v, w5b4, s54, t);
    } else if (x < 136) {
        int i = (x - 130) * 256 + t;
        if (i < 1280) {
            int k = i / 10, c = i % 10;
            float acc = 0.f;
            for (int j = 0; j < 128; ++j) acc += W3[k * 128 + j] * Wc[j * 10 + c];
            W3c[i] = acc;
        } else if (i < 1290) {
            int c = i - 1280;
            float acc = 0.f;
            for (int j = 0; j < 128; ++j) acc += b3[j] * Wc[j * 10 + c];
            b3c[c] = acc;
        }
    } else if (x == 136) {
        if (t < 128) zeros[t] = 0.f;
    } else {                                   // x = 137..141: zero 1152 ints
        int i = (x - 137) * 256 + t;
        if (i < 1152) zint[i] = 0;
    }
}

// ---------------- stage 1: hyperedge -> node (2-edge pipeline) --------------
__launch_bounds__(256)
__global__ void attn_s1(const float* __restrict__ vf,          // N x 128 f32
                        const unsigned int* __restrict__ kv,   // M x 128 words (kt|v)
                        const float* __restrict__ ck,          // M
                        const int* __restrict__ off, const int* __restrict__ adj,
                        const int* __restrict__ nperm,
                        unsigned int* __restrict__ fv,         // N x 64 words
                        int nseg, float scale) {
    int slot = (blockIdx.x * blockDim.x + threadIdx.x) >> 4;
    int j = threadIdx.x & 15;
    if (slot >= nseg) return;
    int seg = nperm[slot];
    int beg = off[seg], end = off[seg + 1];
    const f32x4* qp = (const f32x4*)(vf + (size_t)seg * 128 + 8 * j);
    f32x4 qa4 = __builtin_nontemporal_load(qp);
    f32x4 qb4 = __builtin_nontemporal_load(qp + 1);
    float4 qa = {qa4.x, qa4.y, qa4.z, qa4.w};
    float4 qb = {qb4.x, qb4.y, qb4.z, qb4.w};
    float m = -INFINITY, l = 0.f;
    float a[8] = {};
    int i = beg;
    const int cnt = end - beg;
    if (cnt >= 2) {
        int s0 = adj[i], s1 = adj[i + 1];
        uint4 kw0 = ((const uint4*)(kv + (size_t)s0 * 128))[j];
        uint4 vw0 = ((const uint4*)(kv + (size_t)s0 * 128 + 64))[j];
        float c0 = ck[s0];
        uint4 kw1 = ((const uint4*)(kv + (size_t)s1 * 128))[j];
        uint4 vw1 = ((const uint4*)(kv + (size_t)s1 * 128 + 64))[j];
        float c1 = ck[s1];
        for (; i + 1 < end; i += 2) {
            uint4 ka = kw0, va = vw0, kb = kw1, vb = vw1;
            float ca = c0, cb = c1;
            if (i + 3 < end) {                     // prefetch next pair
                int t0 = adj[i + 2], t1 = adj[i + 3];
                kw0 = ((const uint4*)(kv + (size_t)t0 * 128))[j];
                vw0 = ((const uint4*)(kv + (size_t)t0 * 128 + 64))[j];
                c0 = ck[t0];
                kw1 = ((const uint4*)(kv + (size_t)t1 * 128))[j];
                vw1 = ((const uint4*)(kv + (size_t)t1 * 128 + 64))[j];
                c1 = ck[t1];
            } else if (i + 2 < end) {              // prefetch odd tail
                int t0 = adj[i + 2];
                kw0 = ((const uint4*)(kv + (size_t)t0 * 128))[j];
                vw0 = ((const uint4*)(kv + (size_t)t0 * 128 + 64))[j];
                c0 = ck[t0];
            }
            float d1 = dot8(ka, qa, qb);
            float d2 = dot8(kb, qa, qb);
            d1 += __shfl_xor(d1, 8); d2 += __shfl_xor(d2, 8);
            d1 += __shfl_xor(d1, 4); d2 += __shfl_xor(d2, 4);
            d1 += __shfl_xor(d1, 2); d2 += __shfl_xor(d2, 2);
            d1 += __shfl_xor(d1, 1); d2 += __shfl_xor(d2, 1);
            d1 += ca; d2 += cb;
            d1 = (d1 >= 0.f ? d1 : 0.01f * d1) * scale;
            d2 = (d2 >= 0.f ? d2 : 0.01f * d2) * scale;
            float mn = fmaxf(fmaxf(m, d1), d2);
            float r  = __expf(m - mn);             // first pair: exp(-inf)=0
            float p1 = __expf(d1 - mn);
            float p2 = __expf(d2 - mn);
            l = l * r + p1 + p2;
            float v1[8], v2[8];
            unpack8(va, v1); unpack8(vb, v2);
            #pragma unroll
            for (int t = 0; t < 8; ++t)
                a[t] = fmaf(p2, v2[t], fmaf(p1, v1[t], a[t] * r));
            m = mn;
        }
        if (i < end) {                             // odd tail (prefetched slot 0)
            float d = dot8(kw0, qa, qb);
            d = red16(d);
            d += c0;
            d = (d >= 0.f ? d : 0.01f * d) * scale;
            float mn = fmaxf(m, d);
            float r = __expf(m - mn);
            float p = __expf(d - mn);
            l = l * r + p;
            float v1[8]; unpack8(vw0, v1);
            #pragma unroll
            for (int t = 0; t < 8; ++t)
                a[t] = fmaf(p, v1[t], a[t] * r);
            m = mn;
        }
    } else if (cnt == 1) {
        int s0 = adj[i];
        uint4 kw0 = ((const uint4*)(kv + (size_t)s0 * 128))[j];
        uint4 vw0 = ((const uint4*)(kv + (size_t)s0 * 128 + 64))[j];
        float d = dot8(kw0, qa, qb);
        d = red16(d);
        d += ck[s0];
        d = (d >= 0.f ? d : 0.01f * d) * scale;
        l = 1.f;
        float v1[8]; unpack8(vw0, v1);
        #pragma unroll
        for (int t = 0; t < 8; ++t) a[t] = v1[t];
    }
    float inv = (l > 0.f) ? 1.f / l : 0.f;
    u32x4 o;
    o.x = f2bf(a[0] * inv) | (f2bf(a[1] * inv) << 16);
    o.y = f2bf(a[2] * inv) | (f2bf(a[3] * inv) << 16);
    o.z = f2bf(a[4] * inv) | (f2bf(a[5] * inv) << 16);
    o.w = f2bf(a[6] * inv) | (f2bf(a[7] * inv) << 16);
    __builtin_nontemporal_store(o, (u32x4*)(fv + (size_t)seg * 64 + 4 * j));
}

// ---------------- stage 2: node -> hyperedge (fused head) -------------------
// q now bf16 (64-word rows); merge+head parallelized over 64 lanes of wave 0.
__launch_bounds__(256)
__global__ void attn_s2(const unsigned int* __restrict__ qtb,  // M x 64 words
                        const float* __restrict__ cvec,
                        const unsigned int* __restrict__ fv,
                        const int* __restrict__ off, const int* __restrict__ adj,
                        const float* __restrict__ W3c, const float* __restrict__ b3c,
                        const float* __restrict__ bc, float* __restrict__ out,
                        float scale) {
    __shared__ float sm[16], sl[16];
    __shared__ float sacc[16][16][9];
    const int seg = blockIdx.x;
    const int g = threadIdx.x >> 4;
    const int j = threadIdx.x & 15;
    const int beg = off[seg], end = off[seg + 1];
    const u32x4* qp = (const u32x4*)(qtb + (size_t)seg * 64 + 4 * j);
    u32x4 qw4 = __builtin_nontemporal_load(qp);
    uint4 qw = {qw4.x, qw4.y, qw4.z, qw4.w};
    float qv[8]; unpack8(qw, qv);
    float4 qa = {qv[0], qv[1], qv[2], qv[3]};
    float4 qb = {qv[4], qv[5], qv[6], qv[7]};
    const float cadd = cvec[seg];
    float m = -INFINITY, l = 0.f;
    float a[8] = {};
    int it = beg + g;
    if (it + 16 < end) {
        int s0 = adj[it], s1 = adj[it + 16];
        uint4 rw0 = ((const uint4*)(fv + (size_t)s0 * 64))[j];
        uint4 rw1 = ((const uint4*)(fv + (size_t)s1 * 64))[j];
        for (; it + 16 < end; it += 32) {
            uint4 ra = rw0, rb = rw1;
            if (it + 48 < end) {
                int t0 = adj[it + 32], t1 = adj[it + 48];
                rw0 = ((const uint4*)(fv + (size_t)t0 * 64))[j];
                rw1 = ((const uint4*)(fv + (size_t)t1 * 64))[j];
            } else if (it + 32 < end) {
                int t0 = adj[it + 32];
                rw0 = ((const uint4*)(fv + (size_t)t0 * 64))[j];
            }
            float v1[8], v2[8];
            unpack8(ra, v1); unpack8(rb, v2);
            float d1 = v1[0] * qa.x + v1[1] * qa.y + v1[2] * qa.z + v1[3] * qa.w
                     + v1[4] * qb.x + v1[5] * qb.y + v1[6] * qb.z + v1[7] * qb.w;
            float d2 = v2[0] * qa.x + v2[1] * qa.y + v2[2] * qa.z + v2[3] * qa.w
                     + v2[4] * qb.x + v2[5] * qb.y + v2[6] * qb.z + v2[7] * qb.w;
            #pragma unroll
            for (int o = 8; o; o >>= 1) { d1 += __shfl_xor(d1, o); d2 += __shfl_xor(d2, o); }
            d1 += cadd; d2 += cadd;
            d1 = (d1 >= 0.f ? d1 : 0.01f * d1) * scale;
            d2 = (d2 >= 0.f ? d2 : 0.01f * d2) * scale;
            float mn = fmaxf(fmaxf(m, d1), d2);
            float r  = __expf(m - mn);
            float p1 = __expf(d1 - mn);
            float p2 = __expf(d2 - mn);
            l = l * r + p1 + p2;
            #pragma unroll
            for (int t = 0; t < 8; ++t)
                a[t] = fmaf(p2, v2[t], fmaf(p1, v1[t], a[t] * r));
            m = mn;
        }
        if (it < end) {
            float v1[8]; unpack8(rw0, v1);
            float d = v1[0] * qa.x + v1[1] * qa.y + v1[2] * qa.z + v1[3] * qa.w
                    + v1[4] * qb.x + v1[5] * qb.y + v1[6] * qb.z + v1[7] * qb.w;
            d = red16(d);
            d += cadd;
            d = (d >= 0.f ? d : 0.01f * d) * scale;
            float mn = fmaxf(m, d);
            float r = __expf(m - mn);
            float p = __expf(d - mn);
            l = l * r + p;
            #pragma unroll
            for (int t = 0; t < 8; ++t) a[t] = fmaf(p, v1[t], a[t] * r);
            m = mn;
        }
    } else if (it < end) {
        int s0 = adj[it];
        uint4 rw0 = ((const uint4*)(fv + (size_t)s0 * 64))[j];
        float v1[8]; unpack8(rw0, v1);
        float d = v1[0] * qa.x + v1[1] * qa.y + v1[2] * qa.z + v1[3] * qa.w
                + v1[4] * qb.x + v1[5] * qb.y + v1[6] * qb.z + v1[7] * qb.w;
        d = red16(d);
        d += cadd;
        d = (d >= 0.f ? d : 0.01f * d) * scale;
        m = d; l = 1.f;
        #pragma unroll
        for (int t = 0; t < 8; ++t) a[t] = v1[t];
    }
    if (j == 0) { sm[g] = m; sl[g] = l; }
    #pragma unroll
    for (int t = 0; t < 8; ++t) sacc[g][j][t] = a[t];
    __syncthreads();
    if (threadIdx.x < 64) {                    // wave 0: parallel merge
        const int t16 = threadIdx.x & 15;      // output dim slice
        const int qtr = threadIdx.x >> 4;      // group quarter 0..3
        float M2 = -INFINITY;
        #pragma unroll 4
        for (int gg = 0; gg < 16; ++gg) if (sl[gg] > 0.f) M2 = fmaxf(M2, sm[gg]);
        float L = 0.f;
        float acc[8] = {};
        #pragma unroll
        for (int gq = 0; gq < 4; ++gq) {       // this quarter's 4 groups
            int gg = qtr * 4 + gq;
            float f = (sl[gg] > 0.f) ? __expf(sm[gg] - M2) : 0.f;
            L += f * sl[gg];
            #pragma unroll
            for (int t = 0; t < 8; ++t) acc[t] += f * sacc[gg][t16][t];
        }
        // reduce across quarters (lanes with same t16)
        #pragma unroll
        for (int o = 16; o < 64; o <<= 1) {
            L += __shfl_xor(L, o);
            #pragma unroll
            for (int t = 0; t < 8; ++t) acc[t] += __shfl_xor(acc[t], o);
        }
        float inv = (L > 0.f) ? 1.f / L : 0.f;
        float fl  = (L > 0.f) ? 1.f : 0.f;
        #pragma unroll
        for (int t = 0; t < 8; ++t) acc[t] *= inv;
        if (qtr == 0) {                        // lanes 0-15: fused head
            float pp[10];
            #pragma unroll
            for (int c = 0; c < 10; ++c) {
                float s = 0.f;
                #pragma unroll
                for (int t = 0; t < 8; ++t)
                    s = fmaf(acc[t], W3c[(8 * t16 + t) * 10 + c], s);
                pp[c] = s;
            }
            #pragma unroll
            for (int o = 8; o; o >>= 1) {
                #pragma unroll
                for (int c = 0; c < 10; ++c) pp[c] += __shfl_xor(pp[c], o);
            }
            if (t16 == 0) {
                #pragma unroll
                for (int c = 0; c < 10; ++c)
                    out[(size_t)seg * 10 + c] = pp[c] + fl * b3c[c] + bc[c];
            }
        }
    }
}

extern "C" void kernel_launch(void* const* d_in, const int* in_sizes, int n_in,
                              void* d_out, int out_size, void* d_ws, size_t ws_size,
                              hipStream_t stream) {
    const float* vfeat = (const float*)d_in[0];
    const float* efeat = (const float*)d_in[1];
    const int*   he    = (const int*)d_in[2];
    const int*   nd    = (const int*)d_in[3];
    const float* Wfl = (const float*)d_in[6],  *bfl = (const float*)d_in[7];
    const float* W1  = (const float*)d_in[8],  *b1  = (const float*)d_in[9];
    const float* W2  = (const float*)d_in[10], *b2  = (const float*)d_in[11];
    const float* W3  = (const float*)d_in[12], *b3  = (const float*)d_in[13];
    const float* W4  = (const float*)d_in[14], *b4  = (const float*)d_in[15];
    const float* W5  = (const float*)d_in[16], *b5  = (const float*)d_in[17];
    const float* W6  = (const float*)d_in[18], *b6  = (const float*)d_in[19];
    const float* Wc  = (const float*)d_in[20], *bc  = (const float*)d_in[21];
    float* out = (float*)d_out;
    float* ws  = (float*)d_ws;

    const int M = HY_M, N = HY_N, E = HY_E;

    // -------- workspace layout (float units) --------
    float* c_e   = ws + 0;         // 10,000
    float* ck    = ws + 10000;     // 10,000
    float* W2T   = ws + 20000;     // 16384
    float* W4T   = ws + 36384;     // 16384
    float* W12   = ws + 52768;     // 16384
    float* W54   = ws + 69152;     // 16384
    float* Wk    = ws + 85536;     // 16384
    float* Wv    = ws + 101920;    // 16384
    float* Wq    = ws + 118304;    // 16384
    float* W3c   = ws + 134688;    // 1280
    float* b3c   = ws + 135968;    // 16
    float* b12v  = ws + 135984;    // 128
    float* w1b2  = ws + 136112;    // 128
    float* s12   = ws + 136240;    // 4
    float* b54v  = ws + 136244;    // 128
    float* w5b4  = ws + 136372;    // 128
    float* s54   = ws + 136500;    // 4
    float* bk    = ws + 136504;    // 128
    float* bv    = ws + 136632;    // 128
    float* bq    = ws + 136760;    // 128
    float* u_c   = ws + 136888;    // 128
    float* u_k   = ws + 137016;    // 128
    float* t_c   = ws + 137144;    // 4
    float* t_k   = ws + 137148;    // 4
    float* zeros = ws + 137152;    // 128 (ends 137280)
    unsigned int* qt_bf = (unsigned int*)(ws + 137280);    // M*64 words
    unsigned int* kv_bf = qt_bf + (size_t)M * 64;          // M*128 words
    unsigned int* fv_bf = kv_bf + (size_t)M * 128;         // N*64 words
    int* nd_off = (int*)(fv_bf + (size_t)N * 64);          // 100,001
    int* he_off = nd_off + 100001;                          // 10,001
    int* nd_adj = he_off + 10001;                           // 640,000
    int* he_adj = nd_adj + 640000;                          // 640,000
    int* nperm  = he_adj + 640000;                          // 100,000
    unsigned int* stN = (unsigned int*)(nperm + 100000);    // 640,000
    unsigned int* stM = stN + 640000;                       // 640,000
    int* gcntN = (int*)(stM + 640000);                      // 256
    int* gcntM = gcntN + 256;                               // 256
    int* gcurN = gcntM + 256;                               // 256
    int* gcurM = gcurN + 256;                               // 256
    int* dcnt  = gcurM + 256;                               // 64
    int* gdcur = dcnt + 64;                                 // 64
    int* coffN = gdcur + 64;                                // 256 (197 used)
    int* coffM = coffN + 256;                               // 256 (158 used)

    const float scale = 0.08838834764831843f;  // 1/sqrt(128)
    const int nchunk = (E + 4095) / 4096;      // 157

    // -------- precompute + zeroing (runs first) --------
    prep_a<<<142, 256, 0, stream>>>(W1, b1, W2, b2, W3, b3, W4, b4, W5, b5, Wc,
                                    W2T, W4T, b12v, w1b2, s12, b54v, w5b4, s54,
                                    W3c, b3c, zeros, gcntN);

    // -------- CSR build (both orientations) + degree hist --------
    coarse_hist<<<nchunk, 256, 0, stream>>>(nd, he, gcntN, gcntM, E);
    coarse_scan<<<2, 256, 0, stream>>>(gcntN, gcntM, coffN, coffM, E);
    part_scatter<<<nchunk, 256, 0, stream>>>(nd, he, coffN, coffM,
                                             gcurN, gcurM, stN, stM, E);
    bucket_build<<<NB_N + NB_M, 256, 0, stream>>>(stN, stM, coffN, coffM,
                                                  nd_off, he_off, nd_adj, he_adj,
                                                  dcnt);
    deg_scatter<<<(N + 255) / 256, 256, 0, stream>>>(nd_off, dcnt, gdcur, nperm, N);

    // -------- weight-product GEMMs --------
    gemm_pair<<<dim3(2, 2), 512, 0, stream>>>(W1, W2T, W12, W5, W4T, W54, zeros);
    gemm_trip<<<dim3(2, 4), 512, 0, stream>>>(Wfl, bfl, W54, b54v, W6, b6, W12, b12v,
                                              w1b2, s12, w5b4, s54,
                                              Wk, Wv, Wq, bk, bv, bq,
                                              u_c, u_k, t_c, t_k, zeros);

    // -------- M-row dense layer + dots (y==6) --------
    gemm_m<<<dim3((M + 31) / 32, 7), 256, 0, stream>>>(
        efeat, Wk, bk, Wv, bv, Wq, bq, u_c, t_c, u_k, t_k, c_e, ck,
        (unsigned short*)kv_bf, (unsigned short*)qt_bf, M);

    // -------- stage 1: hyperedge -> node --------
    attn_s1<<<(N * 16 + 255) / 256, 256, 0, stream>>>(
        vfeat, kv_bf, ck, nd_off, nd_adj, nperm, fv_bf, N, scale);

    // -------- stage 2: node -> hyperedge (head fused, bf16 q) --------
    attn_s2<<<M, 256, 0, stream>>>(qt_bf, c_e, fv_bf, he_off, he_adj,
                                   W3c, b3c, bc, out, scale);
}